// Round 1
// baseline (316.677 us; speedup 1.0000x reference)
//
#include <hip/hip_runtime.h>
#include <math.h>

#define HW 784
#define Cc 192
#define Bb 16
#define CO 384
#define KK 9
#define NT 16

__device__ __forceinline__ unsigned f2ord(float f){
  unsigned u = __float_as_uint(f);
  return (u & 0x80000000u) ? ~u : (u | 0x80000000u);
}

// ---- 1. per-(b,c) mean & max over HW ----
__global__ void k_chstats(const float* __restrict__ x, float* __restrict__ chm, float* __restrict__ chx){
  int wid = threadIdx.x >> 6, lane = threadIdx.x & 63;
  int r = blockIdx.x * 4 + wid;               // r in [0, B*C)
  const float* row = x + (size_t)r * HW;
  float s = 0.f, m = -3.4e38f;
  for (int n = lane; n < HW; n += 64){ float v = row[n]; s += v; m = fmaxf(m, v); }
  for (int off = 32; off; off >>= 1){ s += __shfl_xor(s, off); m = fmaxf(m, __shfl_xor(m, off)); }
  if (lane == 0){ chm[r] = s / (float)HW; chx[r] = m; }
}

// ---- 2. channel-attention MLP: ch = sigmoid(mlp(mean)+mlp(max)) ----
__global__ void k_mlp(const float* __restrict__ chm, const float* __restrict__ chx,
                      const float* __restrict__ w1, const float* __restrict__ b1,
                      const float* __restrict__ w2, const float* __restrict__ b2,
                      float* __restrict__ chv){
  int b = blockIdx.x, t = threadIdx.x;
  __shared__ float vm[Cc], vx[Cc], hp[2][12];
  if (t < Cc){ vm[t] = chm[b*Cc + t]; vx[t] = chx[b*Cc + t]; }
  __syncthreads();
  if (t < 24){
    int h = t % 12;
    const float* src = (t < 12) ? vm : vx;
    float a = b1[h];
    for (int c = 0; c < Cc; ++c) a += src[c] * w1[h*Cc + c];
    hp[t/12][h] = fmaxf(a, 0.f);
  }
  __syncthreads();
  if (t < Cc){
    float a = 2.f * b2[t];
    for (int h = 0; h < 12; ++h) a += (hp[0][h] + hp[1][h]) * w2[t*12 + h];
    chv[b*Cc + t] = 1.f / (1.f + expf(-a));
  }
}

// ---- 3. spatial mean/max over C of x*ch ----
__global__ void k_spin(const float* __restrict__ x, const float* __restrict__ chv,
                       float* __restrict__ amean, float* __restrict__ amax){
  int b = blockIdx.x >> 2;
  int n = ((blockIdx.x & 3) << 8) + threadIdx.x;
  if (n >= HW) return;
  const float* xb = x + (size_t)b*Cc*HW + n;
  const float* cb = chv + b*Cc;
  float s = 0.f, m = -3.4e38f;
  for (int c = 0; c < Cc; ++c){ float v = xb[(size_t)c*HW] * cb[c]; s += v; m = fmaxf(m, v); }
  amean[b*HW + n] = s / (float)Cc;
  amax[b*HW + n]  = m;
}

// ---- 4. 7x7 conv (2 in-ch) + sigmoid ----
__global__ void k_conv(const float* __restrict__ amean, const float* __restrict__ amax,
                       const float* __restrict__ wsp, const float* __restrict__ bsp,
                       float* __restrict__ satt){
  int b = blockIdx.x >> 2;
  int n = ((blockIdx.x & 3) << 8) + threadIdx.x;
  if (n >= HW) return;
  int yy = n / 28, xx = n % 28;
  float a = 0.f;
  for (int ky = 0; ky < 7; ++ky){
    int iy = yy + ky - 3; if (iy < 0 || iy >= 28) continue;
    for (int kx = 0; kx < 7; ++kx){
      int ix = xx + kx - 3; if (ix < 0 || ix >= 28) continue;
      int ii = b*HW + iy*28 + ix;
      a += amean[ii]*wsp[ky*7 + kx] + amax[ii]*wsp[49 + ky*7 + kx];
    }
  }
  satt[b*HW + n] = 1.f / (1.f + expf(-(a + bsp[0])));
}

// ---- 5. build-explain attention and apply to original x ----
__global__ __launch_bounds__(256) void k_att(const float* __restrict__ x, const float* __restrict__ chv,
                                             const float* __restrict__ satt, float* __restrict__ xatt){
  int bc = blockIdx.x;              // b*Cc + c
  int b = bc / Cc;
  int t = threadIdx.x, wid = t >> 6, lane = t & 63;
  const float* xr = x + (size_t)bc * HW;
  const float* sr = satt + b * HW;
  float ch = chv[bc];
  float xv[4], vv[4];
  float lmax = -3.4e38f;
  #pragma unroll
  for (int j = 0; j < 4; ++j){
    int n = t + 256*j;
    if (n < HW){
      xv[j] = xr[n];
      float t1 = xv[j] * ch;        // x_ch
      vv[j] = t1 * sr[n];           // att_x
      lmax = fmaxf(lmax, vv[j]);
    }
  }
  __shared__ float red[8];
  for (int off = 32; off; off >>= 1) lmax = fmaxf(lmax, __shfl_xor(lmax, off));
  if (!lane) red[wid] = lmax;
  __syncthreads();
  float vmax = fmaxf(fmaxf(red[0], red[1]), fmaxf(red[2], red[3]));
  float ls = 0.f;
  #pragma unroll
  for (int j = 0; j < 4; ++j){
    int n = t + 256*j;
    if (n < HW){ vv[j] = expf(vv[j] - vmax); ls += vv[j]; }
  }
  for (int off = 32; off; off >>= 1) ls += __shfl_xor(ls, off);
  if (!lane) red[4 + wid] = ls;
  __syncthreads();
  float S = red[4] + red[5] + red[6] + red[7];
  float inv = 1.f / (1.f + 1e-10f * S);     // a/(amax+EPS) == e/(1+EPS*S)
  #pragma unroll
  for (int j = 0; j < 4; ++j){
    int n = t + 256*j;
    if (n < HW){
      float a = vv[j] * inv;
      xatt[(size_t)bc*HW + n] = xv[j] * ((2.f*a - 1.f)*0.025f + 1.f);
    }
  }
}

// ---- 6. normalize x (pre-attention) for KNN; also sq ----
__global__ void k_norm(const float* __restrict__ x, float* __restrict__ xn, float* __restrict__ sqn){
  int b = blockIdx.x >> 2;
  int n = ((blockIdx.x & 3) << 8) + threadIdx.x;
  if (n >= HW) return;
  const float* xb = x + (size_t)b*Cc*HW + n;
  float s = 0.f;
  for (int c = 0; c < Cc; ++c){ float v = xb[(size_t)c*HW]; s += v*v; }
  float nrm = fmaxf(sqrtf(s), 1e-12f);
  float* xo = xn + (size_t)b*Cc*HW + n;
  float sq = 0.f;
  for (int c = 0; c < Cc; ++c){ float v = xb[(size_t)c*HW] / nrm; xo[(size_t)c*HW] = v; sq += v*v; }
  sqn[b*HW + n] = sq;
}

// ---- 7. fused distance + top-9 selection (16 query nodes per block) ----
__global__ __launch_bounds__(256) void k_knn(const float* __restrict__ xn, const float* __restrict__ sqn,
                                             int* __restrict__ idxo){
  int b = blockIdx.x / 49;
  int nt0 = (blockIdx.x % 49) * NT;
  int t = threadIdx.x;
  __shared__ float xnn[Cc][NT];
  __shared__ float sqt[NT];
  __shared__ float dist[NT][800];
  const float* xb = xn + (size_t)b*Cc*HW;
  for (int e = t; e < Cc*NT; e += 256){
    int c = e >> 4, q = e & 15;
    xnn[c][q] = xb[(size_t)c*HW + nt0 + q];
  }
  if (t < NT) sqt[t] = sqn[b*HW + nt0 + t];
  __syncthreads();
  int mb = t * 4;
  if (mb < HW){
    float acc[NT][4];
    #pragma unroll
    for (int q = 0; q < NT; ++q){ acc[q][0]=acc[q][1]=acc[q][2]=acc[q][3]=0.f; }
    for (int c = 0; c < Cc; ++c){
      const float4 xv = *(const float4*)(xb + (size_t)c*HW + mb);
      const float4* wr = (const float4*)&xnn[c][0];
      float4 w0 = wr[0], w1 = wr[1], w2 = wr[2], w3 = wr[3];
      float wvv[NT] = {w0.x,w0.y,w0.z,w0.w, w1.x,w1.y,w1.z,w1.w,
                       w2.x,w2.y,w2.z,w2.w, w3.x,w3.y,w3.z,w3.w};
      #pragma unroll
      for (int q = 0; q < NT; ++q){
        acc[q][0] += wvv[q]*xv.x; acc[q][1] += wvv[q]*xv.y;
        acc[q][2] += wvv[q]*xv.z; acc[q][3] += wvv[q]*xv.w;
      }
    }
    float4 sqm = *(const float4*)(sqn + b*HW + mb);
    float sm[4] = {sqm.x, sqm.y, sqm.z, sqm.w};
    #pragma unroll
    for (int q = 0; q < NT; ++q){
      float4 dv;
      dv.x = sqt[q] + sm[0] - 2.f*acc[q][0];
      dv.y = sqt[q] + sm[1] - 2.f*acc[q][1];
      dv.z = sqt[q] + sm[2] - 2.f*acc[q][2];
      dv.w = sqt[q] + sm[3] - 2.f*acc[q][3];
      *(float4*)&dist[q][mb] = dv;
    }
  }
  __syncthreads();
  int wid = t >> 6, lane = t & 63;
  for (int r = 0; r < 4; ++r){
    int q = wid*4 + r;
    int n = nt0 + q;
    float dvv[13]; int mvv[13];
    #pragma unroll
    for (int i = 0; i < 13; ++i){
      int m = lane + 64*i;
      dvv[i] = (m < HW) ? dist[q][m] : 3.4e38f;
      mvv[i] = m;
    }
    for (int k = 0; k < KK; ++k){
      float bd = dvv[0]; int bi = 0;
      #pragma unroll
      for (int i = 1; i < 13; ++i) if (dvv[i] < bd){ bd = dvv[i]; bi = i; }
      unsigned long long key = ((unsigned long long)f2ord(bd) << 32) | (unsigned)mvv[bi];
      for (int off = 32; off; off >>= 1){
        unsigned long long o = __shfl_xor(key, off);
        if (o < key) key = o;
      }
      int wm = (int)(unsigned)(key & 0xffffffffu);
      if (lane == 0) idxo[((size_t)b*HW + n)*KK + k] = wm;
      if (mvv[bi] == wm) dvv[bi] = 3.4e38f;   // winning lane invalidates
    }
  }
}

// ---- 8a. build combined weight [w1e-w2e ; w2e] (768 x 192) ----
__global__ void k_wp(const float* __restrict__ we, float* __restrict__ Wp){
  int i = blockIdx.x*256 + threadIdx.x;
  if (i >= 768*Cc) return;
  int o = i / Cc, c = i % Cc;
  Wp[i] = (o < CO) ? (we[(size_t)o*384 + c] - we[(size_t)o*384 + Cc + c])
                   : we[(size_t)(o - CO)*384 + Cc + c];
}

// ---- 8b. PQ[b][768][784] = Wp(768x192) @ xatt[b](192x784), fp32 tiled ----
__global__ __launch_bounds__(256) void k_gemm(const float* __restrict__ Wp, const float* __restrict__ X,
                                              float* __restrict__ PQ){
  int b = blockIdx.z, o0 = blockIdx.y*64, n0 = blockIdx.x*64;
  int t = threadIdx.x;
  int tx = t & 15, ty = t >> 4;
  __shared__ float Wt[16][68];
  __shared__ float Xt[16][64];
  const float* Xb = X + (size_t)b*Cc*HW;
  float acc[4][4] = {};
  for (int k0 = 0; k0 < Cc; k0 += 16){
    #pragma unroll
    for (int r = 0; r < 4; ++r){
      int e = t + 256*r;
      int kk = e & 15, oo = e >> 4;
      Wt[kk][oo] = Wp[(size_t)(o0 + oo)*Cc + k0 + kk];
    }
    #pragma unroll
    for (int r = 0; r < 4; ++r){
      int e = t + 256*r;
      int nn = e & 63, kk = e >> 6;
      int n = n0 + nn;
      Xt[kk][nn] = (n < HW) ? Xb[(size_t)(k0 + kk)*HW + n] : 0.f;
    }
    __syncthreads();
    #pragma unroll
    for (int kk = 0; kk < 16; ++kk){
      float4 av = *(const float4*)&Wt[kk][ty*4];
      float4 bv = *(const float4*)&Xt[kk][tx*4];
      float aa[4] = {av.x, av.y, av.z, av.w};
      float bb[4] = {bv.x, bv.y, bv.z, bv.w};
      #pragma unroll
      for (int i = 0; i < 4; ++i)
        #pragma unroll
        for (int j = 0; j < 4; ++j) acc[i][j] += aa[i]*bb[j];
    }
    __syncthreads();
  }
  int nb = n0 + tx*4;
  if (nb < HW){
    #pragma unroll
    for (int i = 0; i < 4; ++i){
      float4 v = make_float4(acc[i][0], acc[i][1], acc[i][2], acc[i][3]);
      *(float4*)(PQ + ((size_t)b*768 + o0 + ty*4 + i)*HW + nb) = v;
    }
  }
}

// ---- 9. epilogue: out = relu(P + b_edge + max_k Q[idx]) ----
__global__ __launch_bounds__(256) void k_edge(const float* __restrict__ PQ, const int* __restrict__ idx,
                                              const float* __restrict__ be, float* __restrict__ out){
  int bo = blockIdx.x;
  int b = bo / CO, o = bo % CO;
  const float* Pr = PQ + ((size_t)b*768 + o)*HW;
  const float* Qr = PQ + ((size_t)b*768 + CO + o)*HW;
  const int* ib = idx + (size_t)b*HW*KK;
  float bev = be[o];
  float* orow = out + ((size_t)b*CO + o)*HW;
  for (int n = threadIdx.x; n < HW; n += 256){
    const int* ip = ib + n*KK;
    float qv = -3.4e38f;
    #pragma unroll
    for (int k = 0; k < KK; ++k) qv = fmaxf(qv, Qr[ip[k]]);
    orow[n] = fmaxf(Pr[n] + bev + qv, 0.f);
  }
}

extern "C" void kernel_launch(void* const* d_in, const int* in_sizes, int n_in,
                              void* d_out, int out_size, void* d_ws, size_t ws_size,
                              hipStream_t stream){
  const float* x   = (const float*)d_in[0];
  const float* we  = (const float*)d_in[1];
  const float* be  = (const float*)d_in[2];
  const float* w1  = (const float*)d_in[3];
  const float* b1  = (const float*)d_in[4];
  const float* w2  = (const float*)d_in[5];
  const float* b2  = (const float*)d_in[6];
  const float* wsp = (const float*)d_in[7];
  const float* bsp = (const float*)d_in[8];
  float* out = (float*)d_out;

  // workspace layout (~57 MiB total)
  float* ws    = (float*)d_ws;
  float* chm   = ws;                 // 3072
  float* chx   = chm + 3072;         // 3072
  float* chv   = chx + 3072;         // 3072
  float* amean = chv + 3072;         // 12544
  float* amax  = amean + 12544;      // 12544
  float* satt  = amax + 12544;       // 12544
  float* sqn   = satt + 12544;       // 12544
  float* Wp    = sqn + 12544;        // 147456
  float* xn    = Wp + 147456;        // 2408448
  float* xatt  = xn + 2408448;       // 2408448
  float* PQ    = xatt + 2408448;     // 9633792
  int*   idx   = (int*)(PQ + 9633792); // 112896 ints

  k_chstats<<<768, 256, 0, stream>>>(x, chm, chx);
  k_mlp<<<16, 192, 0, stream>>>(chm, chx, w1, b1, w2, b2, chv);
  k_spin<<<64, 256, 0, stream>>>(x, chv, amean, amax);
  k_conv<<<64, 256, 0, stream>>>(amean, amax, wsp, bsp, satt);
  k_att<<<3072, 256, 0, stream>>>(x, chv, satt, xatt);
  k_norm<<<64, 256, 0, stream>>>(x, xn, sqn);
  k_knn<<<784, 256, 0, stream>>>(xn, sqn, idx);
  k_wp<<<576, 256, 0, stream>>>(we, Wp);
  k_gemm<<<dim3(13, 12, 16), 256, 0, stream>>>(Wp, xatt, PQ);
  k_edge<<<6144, 256, 0, stream>>>(PQ, idx, be, out);
}

// Round 3
// 296.176 us; speedup vs baseline: 1.0692x; 1.0692x over previous
//
#include <hip/hip_runtime.h>
#include <math.h>

#define HW 784
#define Cc 192
#define Bb 16
#define CO 384
#define KK 9

__device__ __forceinline__ unsigned f2ord(float f){
  unsigned u = __float_as_uint(f);
  return (u & 0x80000000u) ? ~u : (u | 0x80000000u);
}

// ---- 1. per-(b,c) mean & max over HW ----
__global__ void k_chstats(const float* __restrict__ x, float* __restrict__ chm, float* __restrict__ chx){
  int wid = threadIdx.x >> 6, lane = threadIdx.x & 63;
  int r = blockIdx.x * 4 + wid;               // r in [0, B*C)
  const float* row = x + (size_t)r * HW;
  float s = 0.f, m = -3.4e38f;
  for (int n = lane; n < HW; n += 64){ float v = row[n]; s += v; m = fmaxf(m, v); }
  for (int off = 32; off; off >>= 1){ s += __shfl_xor(s, off); m = fmaxf(m, __shfl_xor(m, off)); }
  if (lane == 0){ chm[r] = s / (float)HW; chx[r] = m; }
}

// ---- 2. channel-attention MLP: ch = sigmoid(mlp(mean)+mlp(max)) ----
__global__ void k_mlp(const float* __restrict__ chm, const float* __restrict__ chx,
                      const float* __restrict__ w1, const float* __restrict__ b1,
                      const float* __restrict__ w2, const float* __restrict__ b2,
                      float* __restrict__ chv){
  int b = blockIdx.x, t = threadIdx.x;
  __shared__ float vm[Cc], vx[Cc], hp[2][12];
  if (t < Cc){ vm[t] = chm[b*Cc + t]; vx[t] = chx[b*Cc + t]; }
  __syncthreads();
  if (t < 24){
    int h = t % 12;
    const float* src = (t < 12) ? vm : vx;
    float a = b1[h];
    for (int c = 0; c < Cc; ++c) a += src[c] * w1[h*Cc + c];
    hp[t/12][h] = fmaxf(a, 0.f);
  }
  __syncthreads();
  if (t < Cc){
    float a = 2.f * b2[t];
    for (int h = 0; h < 12; ++h) a += (hp[0][h] + hp[1][h]) * w2[t*12 + h];
    chv[b*Cc + t] = 1.f / (1.f + expf(-a));
  }
}

// ---- 3. spatial mean/max over C of x*ch ----
__global__ void k_spin(const float* __restrict__ x, const float* __restrict__ chv,
                       float* __restrict__ amean, float* __restrict__ amax){
  int b = blockIdx.x >> 2;
  int n = ((blockIdx.x & 3) << 8) + threadIdx.x;
  if (n >= HW) return;
  const float* xb = x + (size_t)b*Cc*HW + n;
  const float* cb = chv + b*Cc;
  float s = 0.f, m = -3.4e38f;
  for (int c = 0; c < Cc; ++c){ float v = xb[(size_t)c*HW] * cb[c]; s += v; m = fmaxf(m, v); }
  amean[b*HW + n] = s / (float)Cc;
  amax[b*HW + n]  = m;
}

// ---- 4. 7x7 conv (2 in-ch) + sigmoid ----
__global__ void k_conv(const float* __restrict__ amean, const float* __restrict__ amax,
                       const float* __restrict__ wsp, const float* __restrict__ bsp,
                       float* __restrict__ satt){
  int b = blockIdx.x >> 2;
  int n = ((blockIdx.x & 3) << 8) + threadIdx.x;
  if (n >= HW) return;
  int yy = n / 28, xx = n % 28;
  float a = 0.f;
  for (int ky = 0; ky < 7; ++ky){
    int iy = yy + ky - 3; if (iy < 0 || iy >= 28) continue;
    for (int kx = 0; kx < 7; ++kx){
      int ix = xx + kx - 3; if (ix < 0 || ix >= 28) continue;
      int ii = b*HW + iy*28 + ix;
      a += amean[ii]*wsp[ky*7 + kx] + amax[ii]*wsp[49 + ky*7 + kx];
    }
  }
  satt[b*HW + n] = 1.f / (1.f + expf(-(a + bsp[0])));
}

// ---- 5. build-explain attention and apply to original x ----
__global__ __launch_bounds__(256) void k_att(const float* __restrict__ x, const float* __restrict__ chv,
                                             const float* __restrict__ satt, float* __restrict__ xatt){
  int bc = blockIdx.x;              // b*Cc + c
  int b = bc / Cc;
  int t = threadIdx.x, wid = t >> 6, lane = t & 63;
  const float* xr = x + (size_t)bc * HW;
  const float* sr = satt + b * HW;
  float ch = chv[bc];
  float xv[4], vv[4];
  float lmax = -3.4e38f;
  #pragma unroll
  for (int j = 0; j < 4; ++j){
    int n = t + 256*j;
    if (n < HW){
      xv[j] = xr[n];
      float t1 = xv[j] * ch;        // x_ch
      vv[j] = t1 * sr[n];           // att_x
      lmax = fmaxf(lmax, vv[j]);
    }
  }
  __shared__ float red[8];
  for (int off = 32; off; off >>= 1) lmax = fmaxf(lmax, __shfl_xor(lmax, off));
  if (!lane) red[wid] = lmax;
  __syncthreads();
  float vmax = fmaxf(fmaxf(red[0], red[1]), fmaxf(red[2], red[3]));
  float ls = 0.f;
  #pragma unroll
  for (int j = 0; j < 4; ++j){
    int n = t + 256*j;
    if (n < HW){ vv[j] = expf(vv[j] - vmax); ls += vv[j]; }
  }
  for (int off = 32; off; off >>= 1) ls += __shfl_xor(ls, off);
  if (!lane) red[4 + wid] = ls;
  __syncthreads();
  float S = red[4] + red[5] + red[6] + red[7];
  float inv = 1.f / (1.f + 1e-10f * S);     // a/(amax+EPS) == e/(1+EPS*S)
  #pragma unroll
  for (int j = 0; j < 4; ++j){
    int n = t + 256*j;
    if (n < HW){
      float a = vv[j] * inv;
      xatt[(size_t)bc*HW + n] = xv[j] * ((2.f*a - 1.f)*0.025f + 1.f);
    }
  }
}

// ---- 6. normalize x (pre-attention) for KNN; also sq ----
__global__ void k_norm(const float* __restrict__ x, float* __restrict__ xn, float* __restrict__ sqn){
  int b = blockIdx.x >> 2;
  int n = ((blockIdx.x & 3) << 8) + threadIdx.x;
  if (n >= HW) return;
  const float* xb = x + (size_t)b*Cc*HW + n;
  float s = 0.f;
  for (int c = 0; c < Cc; ++c){ float v = xb[(size_t)c*HW]; s += v*v; }
  float nrm = fmaxf(sqrtf(s), 1e-12f);
  float* xo = xn + (size_t)b*Cc*HW + n;
  float sq = 0.f;
  for (int c = 0; c < Cc; ++c){ float v = xb[(size_t)c*HW] / nrm; xo[(size_t)c*HW] = v; sq += v*v; }
  sqn[b*HW + n] = sq;
}

// ---- 7a. Gram/distance GEMM: D[b][n][m] = sqn[n] + sqn[m] - 2 * xn[:,n].xn[:,m]
//      128x128 tile per block, 8x8 per thread, fp32 ----
__global__ __launch_bounds__(256) void k_gram(const float* __restrict__ xn, const float* __restrict__ sqn,
                                              float* __restrict__ D){
  int b = blockIdx.z;
  int n0 = blockIdx.y * 128, m0 = blockIdx.x * 128;
  int t = threadIdx.x, tx = t & 15, ty = t >> 4;
  __shared__ float As[16][128];
  __shared__ float Bs[16][128];
  const float* Xb = xn + (size_t)b*Cc*HW;
  float acc[8][8] = {};
  for (int k0 = 0; k0 < Cc; k0 += 16){
    #pragma unroll
    for (int r = 0; r < 2; ++r){
      int lin = (t + r*256) * 4;       // 2048 floats per tile
      int kk = lin >> 7, nn = lin & 127;
      const float* src = Xb + (size_t)(k0 + kk)*HW;
      int n = n0 + nn;
      float4 v = (n < HW) ? *(const float4*)(src + n) : make_float4(0,0,0,0);
      *(float4*)&As[kk][nn] = v;
      int m = m0 + nn;
      float4 w = (m < HW) ? *(const float4*)(src + m) : make_float4(0,0,0,0);
      *(float4*)&Bs[kk][nn] = w;
    }
    __syncthreads();
    #pragma unroll
    for (int kk = 0; kk < 16; ++kk){
      float av[8], bv[8];
      *(float4*)&av[0] = *(const float4*)&As[kk][ty*8];
      *(float4*)&av[4] = *(const float4*)&As[kk][ty*8 + 4];
      *(float4*)&bv[0] = *(const float4*)&Bs[kk][tx*8];
      *(float4*)&bv[4] = *(const float4*)&Bs[kk][tx*8 + 4];
      #pragma unroll
      for (int i = 0; i < 8; ++i)
        #pragma unroll
        for (int j = 0; j < 8; ++j) acc[i][j] += av[i]*bv[j];
    }
    __syncthreads();
  }
  // epilogue: dist = sqn[row] + sqn[col] - 2*acc
  const float* sb = sqn + b*HW;
  float sm[8];
  #pragma unroll
  for (int j = 0; j < 8; ++j){
    int col = m0 + tx*8 + j;
    sm[j] = (col < HW) ? sb[col] : 0.f;
  }
  #pragma unroll
  for (int i = 0; i < 8; ++i){
    int row = n0 + ty*8 + i;
    if (row >= HW) continue;
    float sn = sb[row];
    float* Dr = D + ((size_t)b*HW + row)*HW;
    int col0 = m0 + tx*8;
    if (col0 < HW){                    // 784%4==0 and col0%4==0 -> whole float4 valid
      float4 v0 = make_float4(sn + sm[0] - 2.f*acc[i][0], sn + sm[1] - 2.f*acc[i][1],
                              sn + sm[2] - 2.f*acc[i][2], sn + sm[3] - 2.f*acc[i][3]);
      *(float4*)(Dr + col0) = v0;
      if (col0 + 4 < HW){
        float4 v1 = make_float4(sn + sm[4] - 2.f*acc[i][4], sn + sm[5] - 2.f*acc[i][5],
                                sn + sm[6] - 2.f*acc[i][6], sn + sm[7] - 2.f*acc[i][7]);
        *(float4*)(Dr + col0 + 4) = v1;
      }
    }
  }
}

// ---- 7b. top-9 selection: one wave per row ----
__global__ __launch_bounds__(256) void k_select(const float* __restrict__ D, int* __restrict__ idxo){
  int wid = threadIdx.x >> 6, lane = threadIdx.x & 63;
  int row = blockIdx.x * 4 + wid;            // [0, B*HW)
  const float* Dr = D + (size_t)row * HW;
  float dvv[13]; int mvv[13];
  #pragma unroll
  for (int i = 0; i < 13; ++i){
    int m = lane + 64*i;
    dvv[i] = (m < HW) ? Dr[m] : 3.4e38f;
    mvv[i] = m;
  }
  for (int k = 0; k < KK; ++k){
    float bd = dvv[0]; int bi = 0;
    #pragma unroll
    for (int i = 1; i < 13; ++i) if (dvv[i] < bd){ bd = dvv[i]; bi = i; }
    unsigned long long key = ((unsigned long long)f2ord(bd) << 32) | (unsigned)mvv[bi];
    for (int off = 32; off; off >>= 1){
      unsigned long long o = __shfl_xor(key, off);
      if (o < key) key = o;
    }
    int wm = (int)(unsigned)(key & 0xffffffffu);
    if (lane == 0) idxo[(size_t)row*KK + k] = wm;
    if (mvv[bi] == wm) dvv[bi] = 3.4e38f;   // winning lane invalidates
  }
}

// ---- 8a. build combined weight [w1e-w2e ; w2e] (768 x 192) ----
__global__ void k_wp(const float* __restrict__ we, float* __restrict__ Wp){
  int i = blockIdx.x*256 + threadIdx.x;
  if (i >= 768*Cc) return;
  int o = i / Cc, c = i % Cc;
  Wp[i] = (o < CO) ? (we[(size_t)o*384 + c] - we[(size_t)o*384 + Cc + c])
                   : we[(size_t)(o - CO)*384 + Cc + c];
}

// ---- 8b. PQ[b][768][784] = Wp(768x192) @ xatt[b](192x784), fp32 tiled ----
__global__ __launch_bounds__(256) void k_gemm(const float* __restrict__ Wp, const float* __restrict__ X,
                                              float* __restrict__ PQ){
  int b = blockIdx.z, o0 = blockIdx.y*64, n0 = blockIdx.x*64;
  int t = threadIdx.x;
  int tx = t & 15, ty = t >> 4;
  __shared__ float Wt[16][68];
  __shared__ float Xt[16][64];
  const float* Xb = X + (size_t)b*Cc*HW;
  float acc[4][4] = {};
  for (int k0 = 0; k0 < Cc; k0 += 16){
    #pragma unroll
    for (int r = 0; r < 4; ++r){
      int e = t + 256*r;
      int kk = e & 15, oo = e >> 4;
      Wt[kk][oo] = Wp[(size_t)(o0 + oo)*Cc + k0 + kk];
    }
    #pragma unroll
    for (int r = 0; r < 4; ++r){
      int e = t + 256*r;
      int nn = e & 63, kk = e >> 6;
      int n = n0 + nn;
      Xt[kk][nn] = (n < HW) ? Xb[(size_t)(k0 + kk)*HW + n] : 0.f;
    }
    __syncthreads();
    #pragma unroll
    for (int kk = 0; kk < 16; ++kk){
      float4 av = *(const float4*)&Wt[kk][ty*4];
      float4 bv = *(const float4*)&Xt[kk][tx*4];
      float aa[4] = {av.x, av.y, av.z, av.w};
      float bb[4] = {bv.x, bv.y, bv.z, bv.w};
      #pragma unroll
      for (int i = 0; i < 4; ++i)
        #pragma unroll
        for (int j = 0; j < 4; ++j) acc[i][j] += aa[i]*bb[j];
    }
    __syncthreads();
  }
  int nb = n0 + tx*4;
  if (nb < HW){
    #pragma unroll
    for (int i = 0; i < 4; ++i){
      float4 v = make_float4(acc[i][0], acc[i][1], acc[i][2], acc[i][3]);
      *(float4*)(PQ + ((size_t)b*768 + o0 + ty*4 + i)*HW + nb) = v;
    }
  }
}

// ---- 9. epilogue: out = relu(P + b_edge + max_k Q[idx]) ----
__global__ __launch_bounds__(256) void k_edge(const float* __restrict__ PQ, const int* __restrict__ idx,
                                              const float* __restrict__ be, float* __restrict__ out){
  int bo = blockIdx.x;
  int b = bo / CO, o = bo % CO;
  const float* Pr = PQ + ((size_t)b*768 + o)*HW;
  const float* Qr = PQ + ((size_t)b*768 + CO + o)*HW;
  const int* ib = idx + (size_t)b*HW*KK;
  float bev = be[o];
  float* orow = out + ((size_t)b*CO + o)*HW;
  for (int n = threadIdx.x; n < HW; n += 256){
    const int* ip = ib + n*KK;
    float qv = -3.4e38f;
    #pragma unroll
    for (int k = 0; k < KK; ++k) qv = fmaxf(qv, Qr[ip[k]]);
    orow[n] = fmaxf(Pr[n] + bev + qv, 0.f);
  }
}

extern "C" void kernel_launch(void* const* d_in, const int* in_sizes, int n_in,
                              void* d_out, int out_size, void* d_ws, size_t ws_size,
                              hipStream_t stream){
  const float* x   = (const float*)d_in[0];
  const float* we  = (const float*)d_in[1];
  const float* be  = (const float*)d_in[2];
  const float* w1  = (const float*)d_in[3];
  const float* b1  = (const float*)d_in[4];
  const float* w2  = (const float*)d_in[5];
  const float* b2  = (const float*)d_in[6];
  const float* wsp = (const float*)d_in[7];
  const float* bsp = (const float*)d_in[8];
  float* out = (float*)d_out;

  // workspace layout (~60 MiB total)
  float* ws    = (float*)d_ws;
  float* chm   = ws;                 // 3072
  float* chx   = chm + 3072;         // 3072
  float* chv   = chx + 3072;         // 3072
  float* amean = chv + 3072;         // 12544
  float* amax  = amean + 12544;      // 12544
  float* satt  = amax + 12544;       // 12544
  float* sqn   = satt + 12544;       // 12544
  float* Wp    = sqn + 12544;        // 147456
  float* xn    = Wp + 147456;        // 2408448
  float* xatt  = xn + 2408448;       // 2408448
  int*   idx   = (int*)(xatt + 2408448); // 112896 ints
  float* D     = (float*)(idx + 112896); // 9834496 floats (aliased with PQ)
  float* PQ    = D;                  // 9633792 floats (written after D consumed)

  k_chstats<<<768, 256, 0, stream>>>(x, chm, chx);
  k_mlp<<<16, 192, 0, stream>>>(chm, chx, w1, b1, w2, b2, chv);
  k_spin<<<64, 256, 0, stream>>>(x, chv, amean, amax);
  k_conv<<<64, 256, 0, stream>>>(amean, amax, wsp, bsp, satt);
  k_att<<<3072, 256, 0, stream>>>(x, chv, satt, xatt);
  k_norm<<<64, 256, 0, stream>>>(x, xn, sqn);
  k_gram<<<dim3(7, 7, 16), 256, 0, stream>>>(xn, sqn, D);
  k_select<<<3136, 256, 0, stream>>>(D, idx);
  k_wp<<<576, 256, 0, stream>>>(we, Wp);
  k_gemm<<<dim3(13, 12, 16), 256, 0, stream>>>(Wp, xatt, PQ);
  k_edge<<<6144, 256, 0, stream>>>(PQ, idx, be, out);
}

// Round 5
// 227.806 us; speedup vs baseline: 1.3901x; 1.3001x over previous
//
#include <hip/hip_runtime.h>
#include <math.h>

#define HW 784
#define Cc 192
#define Bb 16
#define CO 384
#define KK 9

typedef __attribute__((ext_vector_type(8))) short bf16x8;
typedef __attribute__((ext_vector_type(4))) float f32x4;

__device__ __forceinline__ unsigned f2ord(float f){
  unsigned u = __float_as_uint(f);
  return (u & 0x80000000u) ? ~u : (u | 0x80000000u);
}

__device__ __forceinline__ unsigned short b16rne(float v){
  unsigned u = __float_as_uint(v);
  unsigned r = u + 0x7FFFu + ((u >> 16) & 1u);
  return (unsigned short)(r >> 16);
}

// ---- 1. per-(b,c) mean & max over HW ----
__global__ void k_chstats(const float* __restrict__ x, float* __restrict__ chm, float* __restrict__ chx){
  int wid = threadIdx.x >> 6, lane = threadIdx.x & 63;
  int r = blockIdx.x * 4 + wid;               // r in [0, B*C)
  const float* row = x + (size_t)r * HW;
  float s = 0.f, m = -3.4e38f;
  for (int n = lane; n < HW; n += 64){ float v = row[n]; s += v; m = fmaxf(m, v); }
  for (int off = 32; off; off >>= 1){ s += __shfl_xor(s, off); m = fmaxf(m, __shfl_xor(m, off)); }
  if (lane == 0){ chm[r] = s / (float)HW; chx[r] = m; }
}

// ---- 2. channel-attention MLP: ch = sigmoid(mlp(mean)+mlp(max)) ----
__global__ void k_mlp(const float* __restrict__ chm, const float* __restrict__ chx,
                      const float* __restrict__ w1, const float* __restrict__ b1,
                      const float* __restrict__ w2, const float* __restrict__ b2,
                      float* __restrict__ chv){
  int b = blockIdx.x, t = threadIdx.x;
  __shared__ float vm[Cc], vx[Cc], hp[2][12];
  if (t < Cc){ vm[t] = chm[b*Cc + t]; vx[t] = chx[b*Cc + t]; }
  __syncthreads();
  if (t < 24){
    int h = t % 12;
    const float* src = (t < 12) ? vm : vx;
    float a = b1[h];
    for (int c = 0; c < Cc; ++c) a += src[c] * w1[h*Cc + c];
    hp[t/12][h] = fmaxf(a, 0.f);
  }
  __syncthreads();
  if (t < Cc){
    float a = 2.f * b2[t];
    for (int h = 0; h < 12; ++h) a += (hp[0][h] + hp[1][h]) * w2[t*12 + h];
    chv[b*Cc + t] = 1.f / (1.f + expf(-a));
  }
}

// ---- 3. spatial mean/max over C of x*ch ----
__global__ void k_spin(const float* __restrict__ x, const float* __restrict__ chv,
                       float* __restrict__ amean, float* __restrict__ amax){
  int b = blockIdx.x >> 2;
  int n = ((blockIdx.x & 3) << 8) + threadIdx.x;
  if (n >= HW) return;
  const float* xb = x + (size_t)b*Cc*HW + n;
  const float* cb = chv + b*Cc;
  float s = 0.f, m = -3.4e38f;
  for (int c = 0; c < Cc; ++c){ float v = xb[(size_t)c*HW] * cb[c]; s += v; m = fmaxf(m, v); }
  amean[b*HW + n] = s / (float)Cc;
  amax[b*HW + n]  = m;
}

// ---- 4. 7x7 conv (2 in-ch) + sigmoid ----
__global__ void k_conv(const float* __restrict__ amean, const float* __restrict__ amax,
                       const float* __restrict__ wsp, const float* __restrict__ bsp,
                       float* __restrict__ satt){
  int b = blockIdx.x >> 2;
  int n = ((blockIdx.x & 3) << 8) + threadIdx.x;
  if (n >= HW) return;
  int yy = n / 28, xx = n % 28;
  float a = 0.f;
  for (int ky = 0; ky < 7; ++ky){
    int iy = yy + ky - 3; if (iy < 0 || iy >= 28) continue;
    for (int kx = 0; kx < 7; ++kx){
      int ix = xx + kx - 3; if (ix < 0 || ix >= 28) continue;
      int ii = b*HW + iy*28 + ix;
      a += amean[ii]*wsp[ky*7 + kx] + amax[ii]*wsp[49 + ky*7 + kx];
    }
  }
  satt[b*HW + n] = 1.f / (1.f + expf(-(a + bsp[0])));
}

// ---- 5. build-explain attention and apply to original x ----
__global__ __launch_bounds__(256) void k_att(const float* __restrict__ x, const float* __restrict__ chv,
                                             const float* __restrict__ satt, float* __restrict__ xatt){
  int bc = blockIdx.x;              // b*Cc + c
  int b = bc / Cc;
  int t = threadIdx.x, wid = t >> 6, lane = t & 63;
  const float* xr = x + (size_t)bc * HW;
  const float* sr = satt + b * HW;
  float ch = chv[bc];
  float xv[4], vv[4];
  float lmax = -3.4e38f;
  #pragma unroll
  for (int j = 0; j < 4; ++j){
    int n = t + 256*j;
    if (n < HW){
      xv[j] = xr[n];
      float t1 = xv[j] * ch;        // x_ch
      vv[j] = t1 * sr[n];           // att_x
      lmax = fmaxf(lmax, vv[j]);
    }
  }
  __shared__ float red[8];
  for (int off = 32; off; off >>= 1) lmax = fmaxf(lmax, __shfl_xor(lmax, off));
  if (!lane) red[wid] = lmax;
  __syncthreads();
  float vmax = fmaxf(fmaxf(red[0], red[1]), fmaxf(red[2], red[3]));
  float ls = 0.f;
  #pragma unroll
  for (int j = 0; j < 4; ++j){
    int n = t + 256*j;
    if (n < HW){ vv[j] = expf(vv[j] - vmax); ls += vv[j]; }
  }
  for (int off = 32; off; off >>= 1) ls += __shfl_xor(ls, off);
  if (!lane) red[4 + wid] = ls;
  __syncthreads();
  float S = red[4] + red[5] + red[6] + red[7];
  float inv = 1.f / (1.f + 1e-10f * S);     // a/(amax+EPS) == e/(1+EPS*S)
  #pragma unroll
  for (int j = 0; j < 4; ++j){
    int n = t + 256*j;
    if (n < HW){
      float a = vv[j] * inv;
      xatt[(size_t)bc*HW + n] = xv[j] * ((2.f*a - 1.f)*0.025f + 1.f);
    }
  }
}

// ---- 6a. column norms of x (pre-attention) ----
__global__ void k_norm(const float* __restrict__ x, float* __restrict__ nrm){
  int b = blockIdx.x >> 2;
  int n = ((blockIdx.x & 3) << 8) + threadIdx.x;
  if (n >= HW) return;
  const float* xb = x + (size_t)b*Cc*HW + n;
  float s = 0.f;
  for (int c = 0; c < Cc; ++c){ float v = xb[(size_t)c*HW]; s += v*v; }
  nrm[b*HW + n] = fmaxf(sqrtf(s), 1e-12f);
}

// ---- 6b. transpose + normalize + split to bf16 hi/lo: Xt[n][c] ----
__global__ __launch_bounds__(256) void k_cvt(const float* __restrict__ x, const float* __restrict__ nrm,
                                             unsigned short* __restrict__ Xth, unsigned short* __restrict__ Xtl){
  int b = blockIdx.z, c0 = blockIdx.y*64, n0 = blockIdx.x*64;
  __shared__ float T[64][65];
  int t = threadIdx.x;
  int nl = (t & 15) * 4, cl = t >> 4;
  const float* xb = x + (size_t)b*Cc*HW;
  #pragma unroll
  for (int r = 0; r < 4; ++r){
    int c_loc = cl + r*16;
    int n = n0 + nl;
    float4 v = (n < HW) ? *(const float4*)(xb + (size_t)(c0 + c_loc)*HW + n) : make_float4(0,0,0,0);
    *(float4*)&T[c_loc][nl] = v;
  }
  __syncthreads();
  int nr = t >> 2, q = t & 3;
  int n_g = n0 + nr;
  if (n_g >= HW) return;
  float nv = nrm[b*HW + n_g];
  unsigned int hw_[8], lw_[8];
  #pragma unroll
  for (int j = 0; j < 8; ++j){
    float v0 = T[q*16 + 2*j][nr] / nv;
    float v1 = T[q*16 + 2*j + 1][nr] / nv;
    unsigned short h0 = b16rne(v0), h1 = b16rne(v1);
    float l0 = v0 - __uint_as_float((unsigned)h0 << 16);
    float l1 = v1 - __uint_as_float((unsigned)h1 << 16);
    hw_[j] = (unsigned)h0 | ((unsigned)h1 << 16);
    lw_[j] = (unsigned)b16rne(l0) | ((unsigned)b16rne(l1) << 16);
  }
  size_t base = ((size_t)b*HW + n_g)*Cc + c0 + q*16;
  *(uint4*)(Xth + base)     = make_uint4(hw_[0], hw_[1], hw_[2], hw_[3]);
  *(uint4*)(Xth + base + 8) = make_uint4(hw_[4], hw_[5], hw_[6], hw_[7]);
  *(uint4*)(Xtl + base)     = make_uint4(lw_[0], lw_[1], lw_[2], lw_[3]);
  *(uint4*)(Xtl + base + 8) = make_uint4(lw_[4], lw_[5], lw_[6], lw_[7]);
}

// ---- 7a. Gram via split-bf16 MFMA: D[b][n][m] = -sum_c xn[c][n]*xn[c][m]
//      128x128 tile, 4 waves (2x2), 16x16x32 bf16 MFMA, K' = 3*192 ----
__global__ __launch_bounds__(256) void k_gram(const unsigned short* __restrict__ Xth,
                                              const unsigned short* __restrict__ Xtl,
                                              float* __restrict__ D){
  int b = blockIdx.z;
  int n0 = blockIdx.y*128, m0 = blockIdx.x*128;
  __shared__ unsigned short Als[8192];   // [128 rows][64 k] bf16, XOR-swizzled
  __shared__ unsigned short Bls[8192];
  int t = threadIdx.x, w = t >> 6, l = t & 63;
  int wr = w >> 1, wc = w & 1;
  f32x4 acc[4][4] = {};
  int nn = t >> 1, half = t & 1;
  size_t bb = (size_t)b*HW*Cc;
  int ra = n0 + nn; if (ra > HW-1) ra = HW-1;
  int rb = m0 + nn; if (rb > HW-1) rb = HW-1;

  for (int cc = 0; cc < 9; ++cc){
    int seg = cc/3, kc0 = (cc%3)*64;
    const unsigned short* As_ = (seg < 2 ? Xth : Xtl) + bb;
    const unsigned short* Bs_ = (seg == 1 ? Xtl : Xth) + bb;
    const uint4* ga = (const uint4*)(As_ + (size_t)ra*Cc + kc0 + half*32);
    const uint4* gb = (const uint4*)(Bs_ + (size_t)rb*Cc + kc0 + half*32);
    uint4 va0 = ga[0], va1 = ga[1], va2 = ga[2], va3 = ga[3];
    uint4 vb0 = gb[0], vb1 = gb[1], vb2 = gb[2], vb3 = gb[3];
    __syncthreads();                     // previous chunk's frag reads done
    int base = nn*128 + half*64;
    int sw = (nn & 7) << 4;
    *(uint4*)((char*)Als + ((base      ) ^ sw)) = va0;
    *(uint4*)((char*)Als + ((base + 16 ) ^ sw)) = va1;
    *(uint4*)((char*)Als + ((base + 32 ) ^ sw)) = va2;
    *(uint4*)((char*)Als + ((base + 48 ) ^ sw)) = va3;
    *(uint4*)((char*)Bls + ((base      ) ^ sw)) = vb0;
    *(uint4*)((char*)Bls + ((base + 16 ) ^ sw)) = vb1;
    *(uint4*)((char*)Bls + ((base + 32 ) ^ sw)) = vb2;
    *(uint4*)((char*)Bls + ((base + 48 ) ^ sw)) = vb3;
    __syncthreads();
    #pragma unroll
    for (int ks = 0; ks < 2; ++ks){
      bf16x8 af[4], bfr[4];
      int kb = ks*64 + (l >> 4)*16;
      #pragma unroll
      for (int mt = 0; mt < 4; ++mt){
        int rl = wr*64 + mt*16 + (l & 15);
        int off = (rl*128 + kb) ^ ((rl & 7) << 4);
        af[mt] = *(const bf16x8*)((const char*)Als + off);
      }
      #pragma unroll
      for (int nt = 0; nt < 4; ++nt){
        int cl2 = wc*64 + nt*16 + (l & 15);
        int off = (cl2*128 + kb) ^ ((cl2 & 7) << 4);
        bfr[nt] = *(const bf16x8*)((const char*)Bls + off);
      }
      #pragma unroll
      for (int mt = 0; mt < 4; ++mt)
        #pragma unroll
        for (int nt = 0; nt < 4; ++nt)
          acc[mt][nt] = __builtin_amdgcn_mfma_f32_16x16x32_bf16(af[mt], bfr[nt], acc[mt][nt], 0, 0, 0);
    }
  }
  // store D = -G ; C/D layout: col = lane&15, row = (lane>>4)*4 + reg
  #pragma unroll
  for (int mt = 0; mt < 4; ++mt){
    #pragma unroll
    for (int nt = 0; nt < 4; ++nt){
      int col = m0 + wc*64 + nt*16 + (l & 15);
      if (col >= HW) continue;
      int row0 = n0 + wr*64 + mt*16 + ((l >> 4) << 2);
      #pragma unroll
      for (int r = 0; r < 4; ++r){
        int row = row0 + r;
        if (row < HW) D[((size_t)b*HW + row)*HW + col] = -acc[mt][nt][r];
      }
    }
  }
}

// ---- 7b. top-9 selection: one wave per row ----
__global__ __launch_bounds__(256) void k_select(const float* __restrict__ D, int* __restrict__ idxo){
  int wid = threadIdx.x >> 6, lane = threadIdx.x & 63;
  int row = blockIdx.x * 4 + wid;            // [0, B*HW)
  const float* Dr = D + (size_t)row * HW;
  float dvv[13]; int mvv[13];
  #pragma unroll
  for (int i = 0; i < 13; ++i){
    int m = lane + 64*i;
    dvv[i] = (m < HW) ? Dr[m] : 3.4e38f;
    mvv[i] = m;
  }
  for (int k = 0; k < KK; ++k){
    float bd = dvv[0]; int bi = 0;
    #pragma unroll
    for (int i = 1; i < 13; ++i) if (dvv[i] < bd){ bd = dvv[i]; bi = i; }
    unsigned long long key = ((unsigned long long)f2ord(bd) << 32) | (unsigned)mvv[bi];
    for (int off = 32; off; off >>= 1){
      unsigned long long o = __shfl_xor(key, off);
      if (o < key) key = o;
    }
    int wm = (int)(unsigned)(key & 0xffffffffu);
    if (lane == 0) idxo[(size_t)row*KK + k] = wm;
    if (mvv[bi] == wm) dvv[bi] = 3.4e38f;   // winning lane invalidates
  }
}

// ---- 8a. build combined weight [w1e-w2e ; w2e] (768 x 192) ----
__global__ void k_wp(const float* __restrict__ we, float* __restrict__ Wp){
  int i = blockIdx.x*256 + threadIdx.x;
  if (i >= 768*Cc) return;
  int o = i / Cc, c = i % Cc;
  Wp[i] = (o < CO) ? (we[(size_t)o*384 + c] - we[(size_t)o*384 + Cc + c])
                   : we[(size_t)(o - CO)*384 + Cc + c];
}

// ---- 8b. PQ[b][768][784] = Wp(768x192) @ xatt[b](192x784), fp32 tiled ----
__global__ __launch_bounds__(256) void k_gemm(const float* __restrict__ Wp, const float* __restrict__ X,
                                              float* __restrict__ PQ){
  int b = blockIdx.z, o0 = blockIdx.y*64, n0 = blockIdx.x*64;
  int t = threadIdx.x;
  int tx = t & 15, ty = t >> 4;
  __shared__ float Wt[16][68];
  __shared__ float Xt[16][64];
  const float* Xb = X + (size_t)b*Cc*HW;
  float acc[4][4] = {};
  for (int k0 = 0; k0 < Cc; k0 += 16){
    #pragma unroll
    for (int r = 0; r < 4; ++r){
      int e = t + 256*r;
      int kk = e & 15, oo = e >> 4;
      Wt[kk][oo] = Wp[(size_t)(o0 + oo)*Cc + k0 + kk];
    }
    #pragma unroll
    for (int r = 0; r < 4; ++r){
      int e = t + 256*r;
      int nn = e & 63, kk = e >> 6;
      int n = n0 + nn;
      Xt[kk][nn] = (n < HW) ? Xb[(size_t)(k0 + kk)*HW + n] : 0.f;
    }
    __syncthreads();
    #pragma unroll
    for (int kk = 0; kk < 16; ++kk){
      float4 av = *(const float4*)&Wt[kk][ty*4];
      float4 bv = *(const float4*)&Xt[kk][tx*4];
      float aa[4] = {av.x, av.y, av.z, av.w};
      float bb[4] = {bv.x, bv.y, bv.z, bv.w};
      #pragma unroll
      for (int i = 0; i < 4; ++i)
        #pragma unroll
        for (int j = 0; j < 4; ++j) acc[i][j] += aa[i]*bb[j];
    }
    __syncthreads();
  }
  int nb = n0 + tx*4;
  if (nb < HW){
    #pragma unroll
    for (int i = 0; i < 4; ++i){
      float4 v = make_float4(acc[i][0], acc[i][1], acc[i][2], acc[i][3]);
      *(float4*)(PQ + ((size_t)b*768 + o0 + ty*4 + i)*HW + nb) = v;
    }
  }
}

// ---- 9. epilogue: out = relu(P + b_edge + max_k Q[idx]) ----
__global__ __launch_bounds__(256) void k_edge(const float* __restrict__ PQ, const int* __restrict__ idx,
                                              const float* __restrict__ be, float* __restrict__ out){
  int bo = blockIdx.x;
  int b = bo / CO, o = bo % CO;
  const float* Pr = PQ + ((size_t)b*768 + o)*HW;
  const float* Qr = PQ + ((size_t)b*768 + CO + o)*HW;
  const int* ib = idx + (size_t)b*HW*KK;
  float bev = be[o];
  float* orow = out + ((size_t)b*CO + o)*HW;
  for (int n = threadIdx.x; n < HW; n += 256){
    const int* ip = ib + n*KK;
    float qv = -3.4e38f;
    #pragma unroll
    for (int k = 0; k < KK; ++k) qv = fmaxf(qv, Qr[ip[k]]);
    orow[n] = fmaxf(Pr[n] + bev + qv, 0.f);
  }
}

extern "C" void kernel_launch(void* const* d_in, const int* in_sizes, int n_in,
                              void* d_out, int out_size, void* d_ws, size_t ws_size,
                              hipStream_t stream){
  const float* x   = (const float*)d_in[0];
  const float* we  = (const float*)d_in[1];
  const float* be  = (const float*)d_in[2];
  const float* w1  = (const float*)d_in[3];
  const float* b1  = (const float*)d_in[4];
  const float* w2  = (const float*)d_in[5];
  const float* b2  = (const float*)d_in[6];
  const float* wsp = (const float*)d_in[7];
  const float* bsp = (const float*)d_in[8];
  float* out = (float*)d_out;

  // workspace layout (~59.9 MiB)
  float* ws    = (float*)d_ws;
  float* chm   = ws;                     // 3072
  float* chx   = chm + 3072;             // 3072
  float* chv   = chx + 3072;             // 3072
  float* amean = chv + 3072;             // 12544
  float* amax  = amean + 12544;          // 12544
  float* satt  = amax + 12544;           // 12544
  float* nrm   = satt + 12544;           // 12544
  float* Wp    = nrm + 12544;            // 147456
  float* xatt  = Wp + 147456;            // 2408448
  unsigned short* Xth = (unsigned short*)(xatt + 2408448); // 2408448 ushorts
  unsigned short* Xtl = Xth + 2408448;   // 2408448 ushorts
  int*   idx   = (int*)(Xtl + 2408448);  // 112896 ints
  float* D     = (float*)(idx + 112896); // 9834496 floats (aliased with PQ)
  float* PQ    = D;                      // 9633792 floats (written after D consumed)

  k_chstats<<<768, 256, 0, stream>>>(x, chm, chx);
  k_mlp<<<16, 192, 0, stream>>>(chm, chx, w1, b1, w2, b2, chv);
  k_spin<<<64, 256, 0, stream>>>(x, chv, amean, amax);
  k_conv<<<64, 256, 0, stream>>>(amean, amax, wsp, bsp, satt);
  k_att<<<3072, 256, 0, stream>>>(x, chv, satt, xatt);
  k_norm<<<64, 256, 0, stream>>>(x, nrm);
  k_cvt<<<dim3(13, 3, 16), 256, 0, stream>>>(x, nrm, Xth, Xtl);
  k_gram<<<dim3(7, 7, 16), 256, 0, stream>>>(Xth, Xtl, D);
  k_select<<<3136, 256, 0, stream>>>(D, idx);
  k_wp<<<576, 256, 0, stream>>>(we, Wp);
  k_gemm<<<dim3(13, 12, 16), 256, 0, stream>>>(Wp, xatt, PQ);
  k_edge<<<6144, 256, 0, stream>>>(PQ, idx, be, out);
}

// Round 6
// 201.602 us; speedup vs baseline: 1.5708x; 1.1300x over previous
//
#include <hip/hip_runtime.h>
#include <math.h>

#define HW 784
#define Cc 192
#define Bb 16
#define CO 384
#define KK 9

typedef __attribute__((ext_vector_type(8))) short bf16x8;
typedef __attribute__((ext_vector_type(4))) float f32x4;

__device__ __forceinline__ unsigned f2ord(float f){
  unsigned u = __float_as_uint(f);
  return (u & 0x80000000u) ? ~u : (u | 0x80000000u);
}

__device__ __forceinline__ unsigned short b16rne(float v){
  unsigned u = __float_as_uint(v);
  unsigned r = u + 0x7FFFu + ((u >> 16) & 1u);
  return (unsigned short)(r >> 16);
}

// ---- 1. per-(b,c) mean & max over HW ----
__global__ void k_chstats(const float* __restrict__ x, float* __restrict__ chm, float* __restrict__ chx){
  int wid = threadIdx.x >> 6, lane = threadIdx.x & 63;
  int r = blockIdx.x * 4 + wid;               // r in [0, B*C)
  const float* row = x + (size_t)r * HW;
  float s = 0.f, m = -3.4e38f;
  for (int n = lane; n < HW; n += 64){ float v = row[n]; s += v; m = fmaxf(m, v); }
  for (int off = 32; off; off >>= 1){ s += __shfl_xor(s, off); m = fmaxf(m, __shfl_xor(m, off)); }
  if (lane == 0){ chm[r] = s / (float)HW; chx[r] = m; }
}

// ---- 2. channel-attention MLP: ch = sigmoid(mlp(mean)+mlp(max)) ----
__global__ void k_mlp(const float* __restrict__ chm, const float* __restrict__ chx,
                      const float* __restrict__ w1, const float* __restrict__ b1,
                      const float* __restrict__ w2, const float* __restrict__ b2,
                      float* __restrict__ chv){
  int b = blockIdx.x, t = threadIdx.x;
  __shared__ float vm[Cc], vx[Cc], hp[2][12];
  if (t < Cc){ vm[t] = chm[b*Cc + t]; vx[t] = chx[b*Cc + t]; }
  __syncthreads();
  if (t < 24){
    int h = t % 12;
    const float* src = (t < 12) ? vm : vx;
    float a = b1[h];
    for (int c = 0; c < Cc; ++c) a += src[c] * w1[h*Cc + c];
    hp[t/12][h] = fmaxf(a, 0.f);
  }
  __syncthreads();
  if (t < Cc){
    float a = 2.f * b2[t];
    for (int h = 0; h < 12; ++h) a += (hp[0][h] + hp[1][h]) * w2[t*12 + h];
    chv[b*Cc + t] = 1.f / (1.f + expf(-a));
  }
}

// ---- 3. spatial mean/max over C of x*ch ----
__global__ void k_spin(const float* __restrict__ x, const float* __restrict__ chv,
                       float* __restrict__ amean, float* __restrict__ amax){
  int b = blockIdx.x >> 2;
  int n = ((blockIdx.x & 3) << 8) + threadIdx.x;
  if (n >= HW) return;
  const float* xb = x + (size_t)b*Cc*HW + n;
  const float* cb = chv + b*Cc;
  float s = 0.f, m = -3.4e38f;
  for (int c = 0; c < Cc; ++c){ float v = xb[(size_t)c*HW] * cb[c]; s += v; m = fmaxf(m, v); }
  amean[b*HW + n] = s / (float)Cc;
  amax[b*HW + n]  = m;
}

// ---- 4. 7x7 conv (2 in-ch) + sigmoid ----
__global__ void k_conv(const float* __restrict__ amean, const float* __restrict__ amax,
                       const float* __restrict__ wsp, const float* __restrict__ bsp,
                       float* __restrict__ satt){
  int b = blockIdx.x >> 2;
  int n = ((blockIdx.x & 3) << 8) + threadIdx.x;
  if (n >= HW) return;
  int yy = n / 28, xx = n % 28;
  float a = 0.f;
  for (int ky = 0; ky < 7; ++ky){
    int iy = yy + ky - 3; if (iy < 0 || iy >= 28) continue;
    for (int kx = 0; kx < 7; ++kx){
      int ix = xx + kx - 3; if (ix < 0 || ix >= 28) continue;
      int ii = b*HW + iy*28 + ix;
      a += amean[ii]*wsp[ky*7 + kx] + amax[ii]*wsp[49 + ky*7 + kx];
    }
  }
  satt[b*HW + n] = 1.f / (1.f + expf(-(a + bsp[0])));
}

// ---- 5. build-explain attention and apply to original x ----
__global__ __launch_bounds__(256) void k_att(const float* __restrict__ x, const float* __restrict__ chv,
                                             const float* __restrict__ satt, float* __restrict__ xatt){
  int bc = blockIdx.x;              // b*Cc + c
  int b = bc / Cc;
  int t = threadIdx.x, wid = t >> 6, lane = t & 63;
  const float* xr = x + (size_t)bc * HW;
  const float* sr = satt + b * HW;
  float ch = chv[bc];
  float xv[4], vv[4];
  float lmax = -3.4e38f;
  #pragma unroll
  for (int j = 0; j < 4; ++j){
    int n = t + 256*j;
    if (n < HW){
      xv[j] = xr[n];
      float t1 = xv[j] * ch;        // x_ch
      vv[j] = t1 * sr[n];           // att_x
      lmax = fmaxf(lmax, vv[j]);
    }
  }
  __shared__ float red[8];
  for (int off = 32; off; off >>= 1) lmax = fmaxf(lmax, __shfl_xor(lmax, off));
  if (!lane) red[wid] = lmax;
  __syncthreads();
  float vmax = fmaxf(fmaxf(red[0], red[1]), fmaxf(red[2], red[3]));
  float ls = 0.f;
  #pragma unroll
  for (int j = 0; j < 4; ++j){
    int n = t + 256*j;
    if (n < HW){ vv[j] = expf(vv[j] - vmax); ls += vv[j]; }
  }
  for (int off = 32; off; off >>= 1) ls += __shfl_xor(ls, off);
  if (!lane) red[4 + wid] = ls;
  __syncthreads();
  float S = red[4] + red[5] + red[6] + red[7];
  float inv = 1.f / (1.f + 1e-10f * S);     // a/(amax+EPS) == e/(1+EPS*S)
  #pragma unroll
  for (int j = 0; j < 4; ++j){
    int n = t + 256*j;
    if (n < HW){
      float a = vv[j] * inv;
      xatt[(size_t)bc*HW + n] = xv[j] * ((2.f*a - 1.f)*0.025f + 1.f);
    }
  }
}

// ---- 6a. column norms of x (pre-attention) ----
__global__ void k_norm(const float* __restrict__ x, float* __restrict__ nrm){
  int b = blockIdx.x >> 2;
  int n = ((blockIdx.x & 3) << 8) + threadIdx.x;
  if (n >= HW) return;
  const float* xb = x + (size_t)b*Cc*HW + n;
  float s = 0.f;
  for (int c = 0; c < Cc; ++c){ float v = xb[(size_t)c*HW]; s += v*v; }
  nrm[b*HW + n] = fmaxf(sqrtf(s), 1e-12f);
}

// ---- 6b. transpose + (optional) normalize + split to bf16 hi/lo: Xt[n][c] ----
__global__ __launch_bounds__(256) void k_cvt(const float* __restrict__ x, const float* __restrict__ nrm,
                                             unsigned short* __restrict__ Xth, unsigned short* __restrict__ Xtl){
  int b = blockIdx.z, c0 = blockIdx.y*64, n0 = blockIdx.x*64;
  __shared__ float T[64][65];
  int t = threadIdx.x;
  int nl = (t & 15) * 4, cl = t >> 4;
  const float* xb = x + (size_t)b*Cc*HW;
  #pragma unroll
  for (int r = 0; r < 4; ++r){
    int c_loc = cl + r*16;
    int n = n0 + nl;
    float4 v = (n < HW) ? *(const float4*)(xb + (size_t)(c0 + c_loc)*HW + n) : make_float4(0,0,0,0);
    *(float4*)&T[c_loc][nl] = v;
  }
  __syncthreads();
  int nr = t >> 2, q = t & 3;
  int n_g = n0 + nr;
  if (n_g >= HW) return;
  float nv = nrm ? nrm[b*HW + n_g] : 1.f;
  unsigned int hw_[8], lw_[8];
  #pragma unroll
  for (int j = 0; j < 8; ++j){
    float v0 = T[q*16 + 2*j][nr] / nv;
    float v1 = T[q*16 + 2*j + 1][nr] / nv;
    unsigned short h0 = b16rne(v0), h1 = b16rne(v1);
    float l0 = v0 - __uint_as_float((unsigned)h0 << 16);
    float l1 = v1 - __uint_as_float((unsigned)h1 << 16);
    hw_[j] = (unsigned)h0 | ((unsigned)h1 << 16);
    lw_[j] = (unsigned)b16rne(l0) | ((unsigned)b16rne(l1) << 16);
  }
  size_t base = ((size_t)b*HW + n_g)*Cc + c0 + q*16;
  *(uint4*)(Xth + base)     = make_uint4(hw_[0], hw_[1], hw_[2], hw_[3]);
  *(uint4*)(Xth + base + 8) = make_uint4(hw_[4], hw_[5], hw_[6], hw_[7]);
  *(uint4*)(Xtl + base)     = make_uint4(lw_[0], lw_[1], lw_[2], lw_[3]);
  *(uint4*)(Xtl + base + 8) = make_uint4(lw_[4], lw_[5], lw_[6], lw_[7]);
}

// ---- 7a. Gram via split-bf16 MFMA: D[b][n][m] = -sum_c xn[c][n]*xn[c][m]
//      128x128 tile, 4 waves (2x2), 16x16x32 bf16 MFMA, K' = 3*192 ----
__global__ __launch_bounds__(256) void k_gram(const unsigned short* __restrict__ Xth,
                                              const unsigned short* __restrict__ Xtl,
                                              float* __restrict__ D){
  int b = blockIdx.z;
  int n0 = blockIdx.y*128, m0 = blockIdx.x*128;
  __shared__ unsigned short Als[8192];   // [128 rows][64 k] bf16, XOR-swizzled
  __shared__ unsigned short Bls[8192];
  int t = threadIdx.x, w = t >> 6, l = t & 63;
  int wr = w >> 1, wc = w & 1;
  f32x4 acc[4][4] = {};
  int nn = t >> 1, half = t & 1;
  size_t bb = (size_t)b*HW*Cc;
  int ra = n0 + nn; if (ra > HW-1) ra = HW-1;
  int rb = m0 + nn; if (rb > HW-1) rb = HW-1;

  for (int cc = 0; cc < 9; ++cc){
    int seg = cc/3, kc0 = (cc%3)*64;
    const unsigned short* As_ = (seg < 2 ? Xth : Xtl) + bb;
    const unsigned short* Bs_ = (seg == 1 ? Xtl : Xth) + bb;
    const uint4* ga = (const uint4*)(As_ + (size_t)ra*Cc + kc0 + half*32);
    const uint4* gb = (const uint4*)(Bs_ + (size_t)rb*Cc + kc0 + half*32);
    uint4 va0 = ga[0], va1 = ga[1], va2 = ga[2], va3 = ga[3];
    uint4 vb0 = gb[0], vb1 = gb[1], vb2 = gb[2], vb3 = gb[3];
    __syncthreads();                     // previous chunk's frag reads done
    int base = nn*128 + half*64;
    int sw = (nn & 7) << 4;
    *(uint4*)((char*)Als + ((base      ) ^ sw)) = va0;
    *(uint4*)((char*)Als + ((base + 16 ) ^ sw)) = va1;
    *(uint4*)((char*)Als + ((base + 32 ) ^ sw)) = va2;
    *(uint4*)((char*)Als + ((base + 48 ) ^ sw)) = va3;
    *(uint4*)((char*)Bls + ((base      ) ^ sw)) = vb0;
    *(uint4*)((char*)Bls + ((base + 16 ) ^ sw)) = vb1;
    *(uint4*)((char*)Bls + ((base + 32 ) ^ sw)) = vb2;
    *(uint4*)((char*)Bls + ((base + 48 ) ^ sw)) = vb3;
    __syncthreads();
    #pragma unroll
    for (int ks = 0; ks < 2; ++ks){
      bf16x8 af[4], bfr[4];
      int kb = ks*64 + (l >> 4)*16;
      #pragma unroll
      for (int mt = 0; mt < 4; ++mt){
        int rl = wr*64 + mt*16 + (l & 15);
        int off = (rl*128 + kb) ^ ((rl & 7) << 4);
        af[mt] = *(const bf16x8*)((const char*)Als + off);
      }
      #pragma unroll
      for (int nt = 0; nt < 4; ++nt){
        int cl2 = wc*64 + nt*16 + (l & 15);
        int off = (cl2*128 + kb) ^ ((cl2 & 7) << 4);
        bfr[nt] = *(const bf16x8*)((const char*)Bls + off);
      }
      #pragma unroll
      for (int mt = 0; mt < 4; ++mt)
        #pragma unroll
        for (int nt = 0; nt < 4; ++nt)
          acc[mt][nt] = __builtin_amdgcn_mfma_f32_16x16x32_bf16(af[mt], bfr[nt], acc[mt][nt], 0, 0, 0);
    }
  }
  // store D = -G ; C/D layout: col = lane&15, row = (lane>>4)*4 + reg
  #pragma unroll
  for (int mt = 0; mt < 4; ++mt){
    #pragma unroll
    for (int nt = 0; nt < 4; ++nt){
      int col = m0 + wc*64 + nt*16 + (l & 15);
      if (col >= HW) continue;
      int row0 = n0 + wr*64 + mt*16 + ((l >> 4) << 2);
      #pragma unroll
      for (int r = 0; r < 4; ++r){
        int row = row0 + r;
        if (row < HW) D[((size_t)b*HW + row)*HW + col] = -acc[mt][nt][r];
      }
    }
  }
}

// ---- 7b. top-9 selection: one wave per row ----
__global__ __launch_bounds__(256) void k_select(const float* __restrict__ D, int* __restrict__ idxo){
  int wid = threadIdx.x >> 6, lane = threadIdx.x & 63;
  int row = blockIdx.x * 4 + wid;            // [0, B*HW)
  const float* Dr = D + (size_t)row * HW;
  float dvv[13]; int mvv[13];
  #pragma unroll
  for (int i = 0; i < 13; ++i){
    int m = lane + 64*i;
    dvv[i] = (m < HW) ? Dr[m] : 3.4e38f;
    mvv[i] = m;
  }
  for (int k = 0; k < KK; ++k){
    float bd = dvv[0]; int bi = 0;
    #pragma unroll
    for (int i = 1; i < 13; ++i) if (dvv[i] < bd){ bd = dvv[i]; bi = i; }
    unsigned long long key = ((unsigned long long)f2ord(bd) << 32) | (unsigned)mvv[bi];
    for (int off = 32; off; off >>= 1){
      unsigned long long o = __shfl_xor(key, off);
      if (o < key) key = o;
    }
    int wm = (int)(unsigned)(key & 0xffffffffu);
    if (lane == 0) idxo[(size_t)row*KK + k] = wm;
    if (mvv[bi] == wm) dvv[bi] = 3.4e38f;   // winning lane invalidates
  }
}

// ---- 8a. build combined weight [w1e-w2e ; w2e] (768 x 192), split bf16 hi/lo ----
__global__ void k_wp(const float* __restrict__ we, unsigned short* __restrict__ Wph,
                     unsigned short* __restrict__ Wpl){
  int i = blockIdx.x*256 + threadIdx.x;
  if (i >= 768*Cc) return;
  int o = i / Cc, c = i % Cc;
  float v = (o < CO) ? (we[(size_t)o*384 + c] - we[(size_t)o*384 + Cc + c])
                     : we[(size_t)(o - CO)*384 + Cc + c];
  unsigned short h = b16rne(v);
  float lo = v - __uint_as_float((unsigned)h << 16);
  Wph[i] = h;
  Wpl[i] = b16rne(lo);
}

// ---- 8b. PQ[b][o][n] = sum_c Wp[o][c]*xatt[n][c] via split-bf16 MFMA
//      (clone of verified k_gram structure; A=Wp rows, B=xattT rows) ----
__global__ __launch_bounds__(256) void k_gemm2(const unsigned short* __restrict__ Wph,
                                               const unsigned short* __restrict__ Wpl,
                                               const unsigned short* __restrict__ XAh,
                                               const unsigned short* __restrict__ XAl,
                                               float* __restrict__ PQ){
  int b = blockIdx.z;
  int o0 = blockIdx.y*128, n0 = blockIdx.x*128;
  __shared__ unsigned short Als[8192];
  __shared__ unsigned short Bls[8192];
  int t = threadIdx.x, w = t >> 6, l = t & 63;
  int wr = w >> 1, wc = w & 1;
  f32x4 acc[4][4] = {};
  int nn = t >> 1, half = t & 1;
  size_t bx = (size_t)b*HW*Cc;
  int ra = o0 + nn;                         // Wp row, < 768 always
  int rb = n0 + nn; if (rb > HW-1) rb = HW-1;

  for (int cc = 0; cc < 9; ++cc){
    int seg = cc/3, kc0 = (cc%3)*64;
    const unsigned short* As_ = (seg < 2 ? Wph : Wpl);
    const unsigned short* Bs_ = (seg == 1 ? XAl : XAh) + bx;
    const uint4* ga = (const uint4*)(As_ + (size_t)ra*Cc + kc0 + half*32);
    const uint4* gb = (const uint4*)(Bs_ + (size_t)rb*Cc + kc0 + half*32);
    uint4 va0 = ga[0], va1 = ga[1], va2 = ga[2], va3 = ga[3];
    uint4 vb0 = gb[0], vb1 = gb[1], vb2 = gb[2], vb3 = gb[3];
    __syncthreads();
    int base = nn*128 + half*64;
    int sw = (nn & 7) << 4;
    *(uint4*)((char*)Als + ((base      ) ^ sw)) = va0;
    *(uint4*)((char*)Als + ((base + 16 ) ^ sw)) = va1;
    *(uint4*)((char*)Als + ((base + 32 ) ^ sw)) = va2;
    *(uint4*)((char*)Als + ((base + 48 ) ^ sw)) = va3;
    *(uint4*)((char*)Bls + ((base      ) ^ sw)) = vb0;
    *(uint4*)((char*)Bls + ((base + 16 ) ^ sw)) = vb1;
    *(uint4*)((char*)Bls + ((base + 32 ) ^ sw)) = vb2;
    *(uint4*)((char*)Bls + ((base + 48 ) ^ sw)) = vb3;
    __syncthreads();
    #pragma unroll
    for (int ks = 0; ks < 2; ++ks){
      bf16x8 af[4], bfr[4];
      int kb = ks*64 + (l >> 4)*16;
      #pragma unroll
      for (int mt = 0; mt < 4; ++mt){
        int rl = wr*64 + mt*16 + (l & 15);
        int off = (rl*128 + kb) ^ ((rl & 7) << 4);
        af[mt] = *(const bf16x8*)((const char*)Als + off);
      }
      #pragma unroll
      for (int nt = 0; nt < 4; ++nt){
        int cl2 = wc*64 + nt*16 + (l & 15);
        int off = (cl2*128 + kb) ^ ((cl2 & 7) << 4);
        bfr[nt] = *(const bf16x8*)((const char*)Bls + off);
      }
      #pragma unroll
      for (int mt = 0; mt < 4; ++mt)
        #pragma unroll
        for (int nt = 0; nt < 4; ++nt)
          acc[mt][nt] = __builtin_amdgcn_mfma_f32_16x16x32_bf16(af[mt], bfr[nt], acc[mt][nt], 0, 0, 0);
    }
  }
  // store: row = o (A-side), col = n (B-side)
  #pragma unroll
  for (int mt = 0; mt < 4; ++mt){
    #pragma unroll
    for (int nt = 0; nt < 4; ++nt){
      int col = n0 + wc*64 + nt*16 + (l & 15);
      if (col >= HW) continue;
      int row0 = o0 + wr*64 + mt*16 + ((l >> 4) << 2);
      #pragma unroll
      for (int r = 0; r < 4; ++r){
        PQ[((size_t)b*768 + row0 + r)*HW + col] = acc[mt][nt][r];
      }
    }
  }
}

// ---- 9. epilogue: out = relu(P + b_edge + max_k Q[idx]) ----
__global__ __launch_bounds__(256) void k_edge(const float* __restrict__ PQ, const int* __restrict__ idx,
                                              const float* __restrict__ be, float* __restrict__ out){
  int bo = blockIdx.x;
  int b = bo / CO, o = bo % CO;
  const float* Pr = PQ + ((size_t)b*768 + o)*HW;
  const float* Qr = PQ + ((size_t)b*768 + CO + o)*HW;
  const int* ib = idx + (size_t)b*HW*KK;
  float bev = be[o];
  float* orow = out + ((size_t)b*CO + o)*HW;
  for (int n = threadIdx.x; n < HW; n += 256){
    const int* ip = ib + n*KK;
    float qv = -3.4e38f;
    #pragma unroll
    for (int k = 0; k < KK; ++k) qv = fmaxf(qv, Qr[ip[k]]);
    orow[n] = fmaxf(Pr[n] + bev + qv, 0.f);
  }
}

extern "C" void kernel_launch(void* const* d_in, const int* in_sizes, int n_in,
                              void* d_out, int out_size, void* d_ws, size_t ws_size,
                              hipStream_t stream){
  const float* x   = (const float*)d_in[0];
  const float* we  = (const float*)d_in[1];
  const float* be  = (const float*)d_in[2];
  const float* w1  = (const float*)d_in[3];
  const float* b1  = (const float*)d_in[4];
  const float* w2  = (const float*)d_in[5];
  const float* b2  = (const float*)d_in[6];
  const float* wsp = (const float*)d_in[7];
  const float* bsp = (const float*)d_in[8];
  float* out = (float*)d_out;

  // workspace layout (~59.9 MiB)
  float* ws    = (float*)d_ws;
  float* chm   = ws;                     // 3072
  float* chx   = chm + 3072;             // 3072
  float* chv   = chx + 3072;             // 3072
  float* amean = chv + 3072;             // 12544
  float* amax  = amean + 12544;          // 12544
  float* satt  = amax + 12544;           // 12544
  float* nrm   = satt + 12544;           // 12544
  unsigned short* Wph = (unsigned short*)(nrm + 12544);    // 147456 ushorts
  unsigned short* Wpl = Wph + 147456;                      // 147456 ushorts
  float* xatt  = (float*)(Wpl + 147456); // 2408448 floats
  unsigned short* Xth = (unsigned short*)(xatt + 2408448); // 2408448 ushorts
  unsigned short* Xtl = Xth + 2408448;   // 2408448 ushorts (reused for xatt cvt)
  int*   idx   = (int*)(Xtl + 2408448);  // 112896 ints
  float* D     = (float*)(idx + 112896); // 9834496 floats (aliased with PQ)
  float* PQ    = D;                      // written after D consumed by k_select

  k_chstats<<<768, 256, 0, stream>>>(x, chm, chx);
  k_mlp<<<16, 192, 0, stream>>>(chm, chx, w1, b1, w2, b2, chv);
  k_spin<<<64, 256, 0, stream>>>(x, chv, amean, amax);
  k_conv<<<64, 256, 0, stream>>>(amean, amax, wsp, bsp, satt);
  k_att<<<3072, 256, 0, stream>>>(x, chv, satt, xatt);
  k_norm<<<64, 256, 0, stream>>>(x, nrm);
  k_cvt<<<dim3(13, 3, 16), 256, 0, stream>>>(x, nrm, Xth, Xtl);
  k_gram<<<dim3(7, 7, 16), 256, 0, stream>>>(Xth, Xtl, D);
  k_select<<<3136, 256, 0, stream>>>(D, idx);          // consume D before PQ overwrite
  k_wp<<<576, 256, 0, stream>>>(we, Wph, Wpl);
  k_cvt<<<dim3(13, 3, 16), 256, 0, stream>>>(xatt, nullptr, Xth, Xtl);  // reuse buffers
  k_gemm2<<<dim3(7, 6, 16), 256, 0, stream>>>(Wph, Wpl, Xth, Xtl, PQ);
  k_edge<<<6144, 256, 0, stream>>>(PQ, idx, be, out);
}

// Round 7
// 172.697 us; speedup vs baseline: 1.8337x; 1.1674x over previous
//
#include <hip/hip_runtime.h>
#include <math.h>

#define HW 784
#define Cc 192
#define Bb 16
#define CO 384
#define KK 9
#define OG 8

typedef __attribute__((ext_vector_type(8))) short bf16x8;
typedef __attribute__((ext_vector_type(4))) float f32x4;

__device__ __forceinline__ unsigned f2ord(float f){
  unsigned u = __float_as_uint(f);
  return (u & 0x80000000u) ? ~u : (u | 0x80000000u);
}

__device__ __forceinline__ unsigned short b16rne(float v){
  unsigned u = __float_as_uint(v);
  unsigned r = u + 0x7FFFu + ((u >> 16) & 1u);
  return (unsigned short)(r >> 16);
}

// ---- 1. per-(b,c) mean & max over HW ----
__global__ void k_chstats(const float* __restrict__ x, float* __restrict__ chm, float* __restrict__ chx){
  int wid = threadIdx.x >> 6, lane = threadIdx.x & 63;
  int r = blockIdx.x * 4 + wid;               // r in [0, B*C)
  const float* row = x + (size_t)r * HW;
  float s = 0.f, m = -3.4e38f;
  for (int n = lane; n < HW; n += 64){ float v = row[n]; s += v; m = fmaxf(m, v); }
  for (int off = 32; off; off >>= 1){ s += __shfl_xor(s, off); m = fmaxf(m, __shfl_xor(m, off)); }
  if (lane == 0){ chm[r] = s / (float)HW; chx[r] = m; }
}

// ---- 2. channel-attention MLP: ch = sigmoid(mlp(mean)+mlp(max)) ----
__global__ void k_mlp(const float* __restrict__ chm, const float* __restrict__ chx,
                      const float* __restrict__ w1, const float* __restrict__ b1,
                      const float* __restrict__ w2, const float* __restrict__ b2,
                      float* __restrict__ chv){
  int b = blockIdx.x, t = threadIdx.x;
  __shared__ float vm[Cc], vx[Cc], hp[2][12];
  if (t < Cc){ vm[t] = chm[b*Cc + t]; vx[t] = chx[b*Cc + t]; }
  __syncthreads();
  if (t < 24){
    int h = t % 12;
    const float* src = (t < 12) ? vm : vx;
    float a = b1[h];
    for (int c = 0; c < Cc; ++c) a += src[c] * w1[h*Cc + c];
    hp[t/12][h] = fmaxf(a, 0.f);
  }
  __syncthreads();
  if (t < Cc){
    float a = 2.f * b2[t];
    for (int h = 0; h < 12; ++h) a += (hp[0][h] + hp[1][h]) * w2[t*12 + h];
    chv[b*Cc + t] = 1.f / (1.f + expf(-a));
  }
}

// ---- 3. spatial mean/max over C of x*ch ----
__global__ void k_spin(const float* __restrict__ x, const float* __restrict__ chv,
                       float* __restrict__ amean, float* __restrict__ amax){
  int b = blockIdx.x >> 2;
  int n = ((blockIdx.x & 3) << 8) + threadIdx.x;
  if (n >= HW) return;
  const float* xb = x + (size_t)b*Cc*HW + n;
  const float* cb = chv + b*Cc;
  float s = 0.f, m = -3.4e38f;
  for (int c = 0; c < Cc; ++c){ float v = xb[(size_t)c*HW] * cb[c]; s += v; m = fmaxf(m, v); }
  amean[b*HW + n] = s / (float)Cc;
  amax[b*HW + n]  = m;
}

// ---- 4. 7x7 conv (2 in-ch) + sigmoid ----
__global__ void k_conv(const float* __restrict__ amean, const float* __restrict__ amax,
                       const float* __restrict__ wsp, const float* __restrict__ bsp,
                       float* __restrict__ satt){
  int b = blockIdx.x >> 2;
  int n = ((blockIdx.x & 3) << 8) + threadIdx.x;
  if (n >= HW) return;
  int yy = n / 28, xx = n % 28;
  float a = 0.f;
  for (int ky = 0; ky < 7; ++ky){
    int iy = yy + ky - 3; if (iy < 0 || iy >= 28) continue;
    for (int kx = 0; kx < 7; ++kx){
      int ix = xx + kx - 3; if (ix < 0 || ix >= 28) continue;
      int ii = b*HW + iy*28 + ix;
      a += amean[ii]*wsp[ky*7 + kx] + amax[ii]*wsp[49 + ky*7 + kx];
    }
  }
  satt[b*HW + n] = 1.f / (1.f + expf(-(a + bsp[0])));
}

// ---- 5. build-explain attention and apply to original x ----
__global__ __launch_bounds__(256) void k_att(const float* __restrict__ x, const float* __restrict__ chv,
                                             const float* __restrict__ satt, float* __restrict__ xatt){
  int bc = blockIdx.x;              // b*Cc + c
  int b = bc / Cc;
  int t = threadIdx.x, wid = t >> 6, lane = t & 63;
  const float* xr = x + (size_t)bc * HW;
  const float* sr = satt + b * HW;
  float ch = chv[bc];
  float xv[4], vv[4];
  float lmax = -3.4e38f;
  #pragma unroll
  for (int j = 0; j < 4; ++j){
    int n = t + 256*j;
    if (n < HW){
      xv[j] = xr[n];
      float t1 = xv[j] * ch;        // x_ch
      vv[j] = t1 * sr[n];           // att_x
      lmax = fmaxf(lmax, vv[j]);
    }
  }
  __shared__ float red[8];
  for (int off = 32; off; off >>= 1) lmax = fmaxf(lmax, __shfl_xor(lmax, off));
  if (!lane) red[wid] = lmax;
  __syncthreads();
  float vmax = fmaxf(fmaxf(red[0], red[1]), fmaxf(red[2], red[3]));
  float ls = 0.f;
  #pragma unroll
  for (int j = 0; j < 4; ++j){
    int n = t + 256*j;
    if (n < HW){ vv[j] = expf(vv[j] - vmax); ls += vv[j]; }
  }
  for (int off = 32; off; off >>= 1) ls += __shfl_xor(ls, off);
  if (!lane) red[4 + wid] = ls;
  __syncthreads();
  float S = red[4] + red[5] + red[6] + red[7];
  float inv = 1.f / (1.f + 1e-10f * S);     // a/(amax+EPS) == e/(1+EPS*S)
  #pragma unroll
  for (int j = 0; j < 4; ++j){
    int n = t + 256*j;
    if (n < HW){
      float a = vv[j] * inv;
      xatt[(size_t)bc*HW + n] = xv[j] * ((2.f*a - 1.f)*0.025f + 1.f);
    }
  }
}

// ---- 6a. column norms of x (pre-attention) ----
__global__ void k_norm(const float* __restrict__ x, float* __restrict__ nrm){
  int b = blockIdx.x >> 2;
  int n = ((blockIdx.x & 3) << 8) + threadIdx.x;
  if (n >= HW) return;
  const float* xb = x + (size_t)b*Cc*HW + n;
  float s = 0.f;
  for (int c = 0; c < Cc; ++c){ float v = xb[(size_t)c*HW]; s += v*v; }
  nrm[b*HW + n] = fmaxf(sqrtf(s), 1e-12f);
}

// ---- 6b. transpose + (optional) normalize + split to bf16 hi/lo: Xt[n][c] ----
__global__ __launch_bounds__(256) void k_cvt(const float* __restrict__ x, const float* __restrict__ nrm,
                                             unsigned short* __restrict__ Xth, unsigned short* __restrict__ Xtl){
  int b = blockIdx.z, c0 = blockIdx.y*64, n0 = blockIdx.x*64;
  __shared__ float T[64][65];
  int t = threadIdx.x;
  int nl = (t & 15) * 4, cl = t >> 4;
  const float* xb = x + (size_t)b*Cc*HW;
  #pragma unroll
  for (int r = 0; r < 4; ++r){
    int c_loc = cl + r*16;
    int n = n0 + nl;
    float4 v = (n < HW) ? *(const float4*)(xb + (size_t)(c0 + c_loc)*HW + n) : make_float4(0,0,0,0);
    *(float4*)&T[c_loc][nl] = v;
  }
  __syncthreads();
  int nr = t >> 2, q = t & 3;
  int n_g = n0 + nr;
  if (n_g >= HW) return;
  float nv = nrm ? nrm[b*HW + n_g] : 1.f;
  unsigned int hw_[8], lw_[8];
  #pragma unroll
  for (int j = 0; j < 8; ++j){
    float v0 = T[q*16 + 2*j][nr] / nv;
    float v1 = T[q*16 + 2*j + 1][nr] / nv;
    unsigned short h0 = b16rne(v0), h1 = b16rne(v1);
    float l0 = v0 - __uint_as_float((unsigned)h0 << 16);
    float l1 = v1 - __uint_as_float((unsigned)h1 << 16);
    hw_[j] = (unsigned)h0 | ((unsigned)h1 << 16);
    lw_[j] = (unsigned)b16rne(l0) | ((unsigned)b16rne(l1) << 16);
  }
  size_t base = ((size_t)b*HW + n_g)*Cc + c0 + q*16;
  *(uint4*)(Xth + base)     = make_uint4(hw_[0], hw_[1], hw_[2], hw_[3]);
  *(uint4*)(Xth + base + 8) = make_uint4(hw_[4], hw_[5], hw_[6], hw_[7]);
  *(uint4*)(Xtl + base)     = make_uint4(lw_[0], lw_[1], lw_[2], lw_[3]);
  *(uint4*)(Xtl + base + 8) = make_uint4(lw_[4], lw_[5], lw_[6], lw_[7]);
}

// ---- 7a. Gram via split-bf16 MFMA: D[b][n][m] = -sum_c xn[c][n]*xn[c][m]
//      128x128 tile, 4 waves (2x2), 16x16x32 bf16 MFMA, K' = 3*192 ----
__global__ __launch_bounds__(256) void k_gram(const unsigned short* __restrict__ Xth,
                                              const unsigned short* __restrict__ Xtl,
                                              float* __restrict__ D){
  int b = blockIdx.z;
  int n0 = blockIdx.y*128, m0 = blockIdx.x*128;
  __shared__ unsigned short Als[8192];   // [128 rows][64 k] bf16, XOR-swizzled
  __shared__ unsigned short Bls[8192];
  int t = threadIdx.x, w = t >> 6, l = t & 63;
  int wr = w >> 1, wc = w & 1;
  f32x4 acc[4][4] = {};
  int nn = t >> 1, half = t & 1;
  size_t bb = (size_t)b*HW*Cc;
  int ra = n0 + nn; if (ra > HW-1) ra = HW-1;
  int rb = m0 + nn; if (rb > HW-1) rb = HW-1;

  for (int cc = 0; cc < 9; ++cc){
    int seg = cc/3, kc0 = (cc%3)*64;
    const unsigned short* As_ = (seg < 2 ? Xth : Xtl) + bb;
    const unsigned short* Bs_ = (seg == 1 ? Xtl : Xth) + bb;
    const uint4* ga = (const uint4*)(As_ + (size_t)ra*Cc + kc0 + half*32);
    const uint4* gb = (const uint4*)(Bs_ + (size_t)rb*Cc + kc0 + half*32);
    uint4 va0 = ga[0], va1 = ga[1], va2 = ga[2], va3 = ga[3];
    uint4 vb0 = gb[0], vb1 = gb[1], vb2 = gb[2], vb3 = gb[3];
    __syncthreads();                     // previous chunk's frag reads done
    int base = nn*128 + half*64;
    int sw = (nn & 7) << 4;
    *(uint4*)((char*)Als + ((base      ) ^ sw)) = va0;
    *(uint4*)((char*)Als + ((base + 16 ) ^ sw)) = va1;
    *(uint4*)((char*)Als + ((base + 32 ) ^ sw)) = va2;
    *(uint4*)((char*)Als + ((base + 48 ) ^ sw)) = va3;
    *(uint4*)((char*)Bls + ((base      ) ^ sw)) = vb0;
    *(uint4*)((char*)Bls + ((base + 16 ) ^ sw)) = vb1;
    *(uint4*)((char*)Bls + ((base + 32 ) ^ sw)) = vb2;
    *(uint4*)((char*)Bls + ((base + 48 ) ^ sw)) = vb3;
    __syncthreads();
    #pragma unroll
    for (int ks = 0; ks < 2; ++ks){
      bf16x8 af[4], bfr[4];
      int kb = ks*64 + (l >> 4)*16;
      #pragma unroll
      for (int mt = 0; mt < 4; ++mt){
        int rl = wr*64 + mt*16 + (l & 15);
        int off = (rl*128 + kb) ^ ((rl & 7) << 4);
        af[mt] = *(const bf16x8*)((const char*)Als + off);
      }
      #pragma unroll
      for (int nt = 0; nt < 4; ++nt){
        int cl2 = wc*64 + nt*16 + (l & 15);
        int off = (cl2*128 + kb) ^ ((cl2 & 7) << 4);
        bfr[nt] = *(const bf16x8*)((const char*)Bls + off);
      }
      #pragma unroll
      for (int mt = 0; mt < 4; ++mt)
        #pragma unroll
        for (int nt = 0; nt < 4; ++nt)
          acc[mt][nt] = __builtin_amdgcn_mfma_f32_16x16x32_bf16(af[mt], bfr[nt], acc[mt][nt], 0, 0, 0);
    }
  }
  // store D = -G ; C/D layout: col = lane&15, row = (lane>>4)*4 + reg
  #pragma unroll
  for (int mt = 0; mt < 4; ++mt){
    #pragma unroll
    for (int nt = 0; nt < 4; ++nt){
      int col = m0 + wc*64 + nt*16 + (l & 15);
      if (col >= HW) continue;
      int row0 = n0 + wr*64 + mt*16 + ((l >> 4) << 2);
      #pragma unroll
      for (int r = 0; r < 4; ++r){
        int row = row0 + r;
        if (row < HW) D[((size_t)b*HW + row)*HW + col] = -acc[mt][nt][r];
      }
    }
  }
}

// ---- 7b. top-9 selection: one wave per row; idx stored [k][b*HW+n] (transposed) ----
__global__ __launch_bounds__(256) void k_select(const float* __restrict__ D, int* __restrict__ idxo){
  int wid = threadIdx.x >> 6, lane = threadIdx.x & 63;
  int row = blockIdx.x * 4 + wid;            // [0, B*HW)
  const float* Dr = D + (size_t)row * HW;
  float dvv[13]; int mvv[13];
  #pragma unroll
  for (int i = 0; i < 13; ++i){
    int m = lane + 64*i;
    dvv[i] = (m < HW) ? Dr[m] : 3.4e38f;
    mvv[i] = m;
  }
  for (int k = 0; k < KK; ++k){
    float bd = dvv[0]; int bi = 0;
    #pragma unroll
    for (int i = 1; i < 13; ++i) if (dvv[i] < bd){ bd = dvv[i]; bi = i; }
    unsigned long long key = ((unsigned long long)f2ord(bd) << 32) | (unsigned)mvv[bi];
    for (int off = 32; off; off >>= 1){
      unsigned long long o = __shfl_xor(key, off);
      if (o < key) key = o;
    }
    int wm = (int)(unsigned)(key & 0xffffffffu);
    if (lane == 0) idxo[(size_t)k*(Bb*HW) + row] = wm;   // [k][row] for coalesced k_edge reads
    if (mvv[bi] == wm) dvv[bi] = 3.4e38f;   // winning lane invalidates
  }
}

// ---- 8a. build combined weight [w1e-w2e ; w2e] (768 x 192), split bf16 hi/lo ----
__global__ void k_wp(const float* __restrict__ we, unsigned short* __restrict__ Wph,
                     unsigned short* __restrict__ Wpl){
  int i = blockIdx.x*256 + threadIdx.x;
  if (i >= 768*Cc) return;
  int o = i / Cc, c = i % Cc;
  float v = (o < CO) ? (we[(size_t)o*384 + c] - we[(size_t)o*384 + Cc + c])
                     : we[(size_t)(o - CO)*384 + Cc + c];
  unsigned short h = b16rne(v);
  float lo = v - __uint_as_float((unsigned)h << 16);
  Wph[i] = h;
  Wpl[i] = b16rne(lo);
}

// ---- 8b. PQ[b][o][n] = sum_c Wp[o][c]*xatt[n][c] via split-bf16 MFMA ----
__global__ __launch_bounds__(256) void k_gemm2(const unsigned short* __restrict__ Wph,
                                               const unsigned short* __restrict__ Wpl,
                                               const unsigned short* __restrict__ XAh,
                                               const unsigned short* __restrict__ XAl,
                                               float* __restrict__ PQ){
  int b = blockIdx.z;
  int o0 = blockIdx.y*128, n0 = blockIdx.x*128;
  __shared__ unsigned short Als[8192];
  __shared__ unsigned short Bls[8192];
  int t = threadIdx.x, w = t >> 6, l = t & 63;
  int wr = w >> 1, wc = w & 1;
  f32x4 acc[4][4] = {};
  int nn = t >> 1, half = t & 1;
  size_t bx = (size_t)b*HW*Cc;
  int ra = o0 + nn;                         // Wp row, < 768 always
  int rb = n0 + nn; if (rb > HW-1) rb = HW-1;

  for (int cc = 0; cc < 9; ++cc){
    int seg = cc/3, kc0 = (cc%3)*64;
    const unsigned short* As_ = (seg < 2 ? Wph : Wpl);
    const unsigned short* Bs_ = (seg == 1 ? XAl : XAh) + bx;
    const uint4* ga = (const uint4*)(As_ + (size_t)ra*Cc + kc0 + half*32);
    const uint4* gb = (const uint4*)(Bs_ + (size_t)rb*Cc + kc0 + half*32);
    uint4 va0 = ga[0], va1 = ga[1], va2 = ga[2], va3 = ga[3];
    uint4 vb0 = gb[0], vb1 = gb[1], vb2 = gb[2], vb3 = gb[3];
    __syncthreads();
    int base = nn*128 + half*64;
    int sw = (nn & 7) << 4;
    *(uint4*)((char*)Als + ((base      ) ^ sw)) = va0;
    *(uint4*)((char*)Als + ((base + 16 ) ^ sw)) = va1;
    *(uint4*)((char*)Als + ((base + 32 ) ^ sw)) = va2;
    *(uint4*)((char*)Als + ((base + 48 ) ^ sw)) = va3;
    *(uint4*)((char*)Bls + ((base      ) ^ sw)) = vb0;
    *(uint4*)((char*)Bls + ((base + 16 ) ^ sw)) = vb1;
    *(uint4*)((char*)Bls + ((base + 32 ) ^ sw)) = vb2;
    *(uint4*)((char*)Bls + ((base + 48 ) ^ sw)) = vb3;
    __syncthreads();
    #pragma unroll
    for (int ks = 0; ks < 2; ++ks){
      bf16x8 af[4], bfr[4];
      int kb = ks*64 + (l >> 4)*16;
      #pragma unroll
      for (int mt = 0; mt < 4; ++mt){
        int rl = wr*64 + mt*16 + (l & 15);
        int off = (rl*128 + kb) ^ ((rl & 7) << 4);
        af[mt] = *(const bf16x8*)((const char*)Als + off);
      }
      #pragma unroll
      for (int nt = 0; nt < 4; ++nt){
        int cl2 = wc*64 + nt*16 + (l & 15);
        int off = (cl2*128 + kb) ^ ((cl2 & 7) << 4);
        bfr[nt] = *(const bf16x8*)((const char*)Bls + off);
      }
      #pragma unroll
      for (int mt = 0; mt < 4; ++mt)
        #pragma unroll
        for (int nt = 0; nt < 4; ++nt)
          acc[mt][nt] = __builtin_amdgcn_mfma_f32_16x16x32_bf16(af[mt], bfr[nt], acc[mt][nt], 0, 0, 0);
    }
  }
  // store: row = o (A-side), col = n (B-side)
  #pragma unroll
  for (int mt = 0; mt < 4; ++mt){
    #pragma unroll
    for (int nt = 0; nt < 4; ++nt){
      int col = n0 + wc*64 + nt*16 + (l & 15);
      if (col >= HW) continue;
      int row0 = o0 + wr*64 + mt*16 + ((l >> 4) << 2);
      #pragma unroll
      for (int r = 0; r < 4; ++r){
        PQ[((size_t)b*768 + row0 + r)*HW + col] = acc[mt][nt][r];
      }
    }
  }
}

// ---- 9. epilogue v2: block = (b, group of 8 o). Q rows staged in LDS;
//      gathers become LDS reads; idx[k][n] reads coalesced, amortized over 8 o ----
__global__ __launch_bounds__(256) void k_edge(const float* __restrict__ PQ, const int* __restrict__ idx,
                                              const float* __restrict__ be, float* __restrict__ out){
  int bid = blockIdx.x;                      // 16 * 48
  int b = bid / (CO/OG), og = bid % (CO/OG);
  int o0 = og * OG;
  __shared__ float Qls[OG][HW + 4];          // pad rows to break stride patterns
  const float* Qbase = PQ + ((size_t)b*768 + CO + o0)*HW;
  int t = threadIdx.x;
  #pragma unroll
  for (int oo = 0; oo < OG; ++oo){
    if (t < 196) *(float4*)&Qls[oo][t*4] = *(const float4*)(Qbase + (size_t)oo*HW + t*4);
  }
  __syncthreads();
  const float* Pbase = PQ + ((size_t)b*768 + o0)*HW;
  float bev[OG];
  #pragma unroll
  for (int oo = 0; oo < OG; ++oo) bev[oo] = be[o0 + oo];
  for (int n = t; n < HW; n += 256){
    int ip[KK];
    #pragma unroll
    for (int k = 0; k < KK; ++k) ip[k] = idx[(size_t)k*(Bb*HW) + b*HW + n];
    float qm[OG];
    #pragma unroll
    for (int oo = 0; oo < OG; ++oo) qm[oo] = -3.4e38f;
    #pragma unroll
    for (int k = 0; k < KK; ++k){
      int j = ip[k];
      #pragma unroll
      for (int oo = 0; oo < OG; ++oo) qm[oo] = fmaxf(qm[oo], Qls[oo][j]);
    }
    #pragma unroll
    for (int oo = 0; oo < OG; ++oo){
      out[((size_t)b*CO + o0 + oo)*HW + n] = fmaxf(Pbase[(size_t)oo*HW + n] + bev[oo] + qm[oo], 0.f);
    }
  }
}

extern "C" void kernel_launch(void* const* d_in, const int* in_sizes, int n_in,
                              void* d_out, int out_size, void* d_ws, size_t ws_size,
                              hipStream_t stream){
  const float* x   = (const float*)d_in[0];
  const float* we  = (const float*)d_in[1];
  const float* be  = (const float*)d_in[2];
  const float* w1  = (const float*)d_in[3];
  const float* b1  = (const float*)d_in[4];
  const float* w2  = (const float*)d_in[5];
  const float* b2  = (const float*)d_in[6];
  const float* wsp = (const float*)d_in[7];
  const float* bsp = (const float*)d_in[8];
  float* out = (float*)d_out;

  // workspace layout (~59.9 MiB)
  float* ws    = (float*)d_ws;
  float* chm   = ws;                     // 3072
  float* chx   = chm + 3072;             // 3072
  float* chv   = chx + 3072;             // 3072
  float* amean = chv + 3072;             // 12544
  float* amax  = amean + 12544;          // 12544
  float* satt  = amax + 12544;           // 12544
  float* nrm   = satt + 12544;           // 12544
  unsigned short* Wph = (unsigned short*)(nrm + 12544);    // 147456 ushorts
  unsigned short* Wpl = Wph + 147456;                      // 147456 ushorts
  float* xatt  = (float*)(Wpl + 147456); // 2408448 floats
  unsigned short* Xth = (unsigned short*)(xatt + 2408448); // 2408448 ushorts
  unsigned short* Xtl = Xth + 2408448;   // 2408448 ushorts (reused for xatt cvt)
  int*   idx   = (int*)(Xtl + 2408448);  // 112896 ints, layout [k][b*HW+n]
  float* D     = (float*)(idx + 112896); // 9834496 floats (aliased with PQ)
  float* PQ    = D;                      // written after D consumed by k_select

  k_chstats<<<768, 256, 0, stream>>>(x, chm, chx);
  k_mlp<<<16, 192, 0, stream>>>(chm, chx, w1, b1, w2, b2, chv);
  k_spin<<<64, 256, 0, stream>>>(x, chv, amean, amax);
  k_conv<<<64, 256, 0, stream>>>(amean, amax, wsp, bsp, satt);
  k_att<<<3072, 256, 0, stream>>>(x, chv, satt, xatt);
  k_norm<<<64, 256, 0, stream>>>(x, nrm);
  k_cvt<<<dim3(13, 3, 16), 256, 0, stream>>>(x, nrm, Xth, Xtl);
  k_gram<<<dim3(7, 7, 16), 256, 0, stream>>>(Xth, Xtl, D);
  k_select<<<3136, 256, 0, stream>>>(D, idx);          // consume D before PQ overwrite
  k_wp<<<576, 256, 0, stream>>>(we, Wph, Wpl);
  k_cvt<<<dim3(13, 3, 16), 256, 0, stream>>>(xatt, nullptr, Xth, Xtl);  // reuse buffers
  k_gemm2<<<dim3(7, 6, 16), 256, 0, stream>>>(Wph, Wpl, Xth, Xtl, PQ);
  k_edge<<<Bb*(CO/OG), 256, 0, stream>>>(PQ, idx, be, out);
}

// Round 8
// 159.260 us; speedup vs baseline: 1.9884x; 1.0844x over previous
//
#include <hip/hip_runtime.h>
#include <math.h>

#define HW 784
#define Cc 192
#define Bb 16
#define CO 384
#define KK 9
#define OG 8

typedef __attribute__((ext_vector_type(8))) short bf16x8;
typedef __attribute__((ext_vector_type(4))) float f32x4;

__device__ __forceinline__ unsigned f2ord(float f){
  unsigned u = __float_as_uint(f);
  return (u & 0x80000000u) ? ~u : (u | 0x80000000u);
}

__device__ __forceinline__ unsigned short b16rne(float v){
  unsigned u = __float_as_uint(v);
  unsigned r = u + 0x7FFFu + ((u >> 16) & 1u);
  return (unsigned short)(r >> 16);
}

// ---- 1. per-(b,c) mean & max over HW ----
__global__ void k_chstats(const float* __restrict__ x, float* __restrict__ chm, float* __restrict__ chx){
  int wid = threadIdx.x >> 6, lane = threadIdx.x & 63;
  int r = blockIdx.x * 4 + wid;               // r in [0, B*C)
  const float* row = x + (size_t)r * HW;
  float s = 0.f, m = -3.4e38f;
  for (int n = lane; n < HW; n += 64){ float v = row[n]; s += v; m = fmaxf(m, v); }
  for (int off = 32; off; off >>= 1){ s += __shfl_xor(s, off); m = fmaxf(m, __shfl_xor(m, off)); }
  if (lane == 0){ chm[r] = s / (float)HW; chx[r] = m; }
}

// ---- 2. channel-attention MLP: ch = sigmoid(mlp(mean)+mlp(max)) ----
__global__ void k_mlp(const float* __restrict__ chm, const float* __restrict__ chx,
                      const float* __restrict__ w1, const float* __restrict__ b1,
                      const float* __restrict__ w2, const float* __restrict__ b2,
                      float* __restrict__ chv){
  int b = blockIdx.x, t = threadIdx.x;
  __shared__ float vm[Cc], vx[Cc], hp[2][12];
  if (t < Cc){ vm[t] = chm[b*Cc + t]; vx[t] = chx[b*Cc + t]; }
  __syncthreads();
  if (t < 24){
    int h = t % 12;
    const float* src = (t < 12) ? vm : vx;
    float a = b1[h];
    for (int c = 0; c < Cc; ++c) a += src[c] * w1[h*Cc + c];
    hp[t/12][h] = fmaxf(a, 0.f);
  }
  __syncthreads();
  if (t < Cc){
    float a = 2.f * b2[t];
    for (int h = 0; h < 12; ++h) a += (hp[0][h] + hp[1][h]) * w2[t*12 + h];
    chv[b*Cc + t] = 1.f / (1.f + expf(-a));
  }
}

// ---- 3. spatial mean/max over C of x*ch  +  column norms of x (fused) ----
__global__ void k_spin(const float* __restrict__ x, const float* __restrict__ chv,
                       float* __restrict__ amean, float* __restrict__ amax,
                       float* __restrict__ nrm){
  int b = blockIdx.x >> 2;
  int n = ((blockIdx.x & 3) << 8) + threadIdx.x;
  if (n >= HW) return;
  const float* xb = x + (size_t)b*Cc*HW + n;
  const float* cb = chv + b*Cc;
  float s = 0.f, m = -3.4e38f, sq = 0.f;
  for (int c = 0; c < Cc; ++c){
    float xv = xb[(size_t)c*HW];
    float v = xv * cb[c];
    s += v; m = fmaxf(m, v); sq += xv*xv;
  }
  amean[b*HW + n] = s / (float)Cc;
  amax[b*HW + n]  = m;
  nrm[b*HW + n]   = fmaxf(sqrtf(sq), 1e-12f);
}

// ---- 4. 7x7 conv (2 in-ch) + sigmoid ----
__global__ void k_conv(const float* __restrict__ amean, const float* __restrict__ amax,
                       const float* __restrict__ wsp, const float* __restrict__ bsp,
                       float* __restrict__ satt){
  int b = blockIdx.x >> 2;
  int n = ((blockIdx.x & 3) << 8) + threadIdx.x;
  if (n >= HW) return;
  int yy = n / 28, xx = n % 28;
  float a = 0.f;
  for (int ky = 0; ky < 7; ++ky){
    int iy = yy + ky - 3; if (iy < 0 || iy >= 28) continue;
    for (int kx = 0; kx < 7; ++kx){
      int ix = xx + kx - 3; if (ix < 0 || ix >= 28) continue;
      int ii = b*HW + iy*28 + ix;
      a += amean[ii]*wsp[ky*7 + kx] + amax[ii]*wsp[49 + ky*7 + kx];
    }
  }
  satt[b*HW + n] = 1.f / (1.f + expf(-(a + bsp[0])));
}

// ---- 5. attention softmax stats per (b,c): vmax and inv = 1/(1+EPS*S) ----
__global__ void k_attstats(const float* __restrict__ x, const float* __restrict__ chv,
                           const float* __restrict__ satt,
                           float* __restrict__ vmaxA, float* __restrict__ invA){
  int wid = threadIdx.x >> 6, lane = threadIdx.x & 63;
  int r = blockIdx.x * 4 + wid;               // b*Cc + c
  int b = r / Cc;
  const float* row = x + (size_t)r * HW;
  const float* sr = satt + b * HW;
  float ch = chv[r];
  float vv[13];
  float m = -3.4e38f;
  #pragma unroll
  for (int i = 0; i < 13; ++i){
    int n = lane + 64*i;
    vv[i] = (n < HW) ? (row[n] * ch) * sr[n] : -3.4e38f;
    m = fmaxf(m, vv[i]);
  }
  for (int off = 32; off; off >>= 1) m = fmaxf(m, __shfl_xor(m, off));
  float s = 0.f;
  #pragma unroll
  for (int i = 0; i < 13; ++i){
    int n = lane + 64*i;
    if (n < HW) s += expf(vv[i] - m);
  }
  for (int off = 32; off; off >>= 1) s += __shfl_xor(s, off);
  if (lane == 0){ vmaxA[r] = m; invA[r] = 1.f / (1.f + 1e-10f * s); }
}

// ---- 6. single transpose pass: x -> Xn (normalized, for KNN) and XA (attention-applied),
//      both split to bf16 hi/lo in [n][c] layout ----
__global__ __launch_bounds__(256) void k_cvt2(const float* __restrict__ x, const float* __restrict__ nrm,
                                              const float* __restrict__ chv, const float* __restrict__ satt,
                                              const float* __restrict__ vmaxA, const float* __restrict__ invA,
                                              unsigned short* __restrict__ Xnh, unsigned short* __restrict__ Xnl,
                                              unsigned short* __restrict__ XAh, unsigned short* __restrict__ XAl){
  int b = blockIdx.z, c0 = blockIdx.y*64, n0 = blockIdx.x*64;
  __shared__ float T[64][65];
  __shared__ float chs[64], vms[64], ivs[64];
  int t = threadIdx.x;
  int nl = (t & 15) * 4, cl = t >> 4;
  const float* xb = x + (size_t)b*Cc*HW;
  #pragma unroll
  for (int r = 0; r < 4; ++r){
    int c_loc = cl + r*16;
    int n = n0 + nl;
    float4 v = (n < HW) ? *(const float4*)(xb + (size_t)(c0 + c_loc)*HW + n) : make_float4(0,0,0,0);
    *(float4*)&T[c_loc][nl] = v;
  }
  if (t < 64){
    chs[t] = chv[b*Cc + c0 + t];
    vms[t] = vmaxA[b*Cc + c0 + t];
    ivs[t] = invA[b*Cc + c0 + t];
  }
  __syncthreads();
  int nr = t >> 2, q = t & 3;
  int n_g = n0 + nr;
  if (n_g >= HW) return;
  float nv = nrm[b*HW + n_g];
  float sr = satt[b*HW + n_g];
  unsigned int nh[8], nlw[8], ah[8], al[8];
  #pragma unroll
  for (int j = 0; j < 8; ++j){
    unsigned int parts[2][2];
    #pragma unroll
    for (int e = 0; e < 2; ++e){
      int cc_ = q*16 + 2*j + e;
      float v = T[cc_][nr];
      // KNN path: v / nrm
      float xnv = v / nv;
      unsigned short h0 = b16rne(xnv);
      float l0 = xnv - __uint_as_float((unsigned)h0 << 16);
      parts[0][e] = (unsigned)h0 | ((unsigned)b16rne(l0) << 16);
      // attention path: same op order as original k_att
      float vvv = (v * chs[cc_]) * sr;
      float ex = expf(vvv - vms[cc_]);
      float a = ex * ivs[cc_];
      float xav = v * ((2.f*a - 1.f)*0.025f + 1.f);
      unsigned short h1 = b16rne(xav);
      float l1 = xav - __uint_as_float((unsigned)h1 << 16);
      parts[1][e] = (unsigned)h1 | ((unsigned)b16rne(l1) << 16);
    }
    nh[j]  = (parts[0][0] & 0xFFFFu) | (parts[0][1] << 16);
    nlw[j] = (parts[0][0] >> 16)     | (parts[0][1] & 0xFFFF0000u);
    ah[j]  = (parts[1][0] & 0xFFFFu) | (parts[1][1] << 16);
    al[j]  = (parts[1][0] >> 16)     | (parts[1][1] & 0xFFFF0000u);
  }
  size_t base = ((size_t)b*HW + n_g)*Cc + c0 + q*16;
  *(uint4*)(Xnh + base)     = make_uint4(nh[0], nh[1], nh[2], nh[3]);
  *(uint4*)(Xnh + base + 8) = make_uint4(nh[4], nh[5], nh[6], nh[7]);
  *(uint4*)(Xnl + base)     = make_uint4(nlw[0], nlw[1], nlw[2], nlw[3]);
  *(uint4*)(Xnl + base + 8) = make_uint4(nlw[4], nlw[5], nlw[6], nlw[7]);
  *(uint4*)(XAh + base)     = make_uint4(ah[0], ah[1], ah[2], ah[3]);
  *(uint4*)(XAh + base + 8) = make_uint4(ah[4], ah[5], ah[6], ah[7]);
  *(uint4*)(XAl + base)     = make_uint4(al[0], al[1], al[2], al[3]);
  *(uint4*)(XAl + base + 8) = make_uint4(al[4], al[5], al[6], al[7]);
}

// ---- 7a. Gram via split-bf16 MFMA: D[b][n][m] = -sum_c xn[c][n]*xn[c][m] ----
__global__ __launch_bounds__(256) void k_gram(const unsigned short* __restrict__ Xth,
                                              const unsigned short* __restrict__ Xtl,
                                              float* __restrict__ D){
  int b = blockIdx.z;
  int n0 = blockIdx.y*128, m0 = blockIdx.x*128;
  __shared__ unsigned short Als[8192];   // [128 rows][64 k] bf16, XOR-swizzled
  __shared__ unsigned short Bls[8192];
  int t = threadIdx.x, w = t >> 6, l = t & 63;
  int wr = w >> 1, wc = w & 1;
  f32x4 acc[4][4] = {};
  int nn = t >> 1, half = t & 1;
  size_t bb = (size_t)b*HW*Cc;
  int ra = n0 + nn; if (ra > HW-1) ra = HW-1;
  int rb = m0 + nn; if (rb > HW-1) rb = HW-1;

  for (int cc = 0; cc < 9; ++cc){
    int seg = cc/3, kc0 = (cc%3)*64;
    const unsigned short* As_ = (seg < 2 ? Xth : Xtl) + bb;
    const unsigned short* Bs_ = (seg == 1 ? Xtl : Xth) + bb;
    const uint4* ga = (const uint4*)(As_ + (size_t)ra*Cc + kc0 + half*32);
    const uint4* gb = (const uint4*)(Bs_ + (size_t)rb*Cc + kc0 + half*32);
    uint4 va0 = ga[0], va1 = ga[1], va2 = ga[2], va3 = ga[3];
    uint4 vb0 = gb[0], vb1 = gb[1], vb2 = gb[2], vb3 = gb[3];
    __syncthreads();                     // previous chunk's frag reads done
    int base = nn*128 + half*64;
    int sw = (nn & 7) << 4;
    *(uint4*)((char*)Als + ((base      ) ^ sw)) = va0;
    *(uint4*)((char*)Als + ((base + 16 ) ^ sw)) = va1;
    *(uint4*)((char*)Als + ((base + 32 ) ^ sw)) = va2;
    *(uint4*)((char*)Als + ((base + 48 ) ^ sw)) = va3;
    *(uint4*)((char*)Bls + ((base      ) ^ sw)) = vb0;
    *(uint4*)((char*)Bls + ((base + 16 ) ^ sw)) = vb1;
    *(uint4*)((char*)Bls + ((base + 32 ) ^ sw)) = vb2;
    *(uint4*)((char*)Bls + ((base + 48 ) ^ sw)) = vb3;
    __syncthreads();
    #pragma unroll
    for (int ks = 0; ks < 2; ++ks){
      bf16x8 af[4], bfr[4];
      int kb = ks*64 + (l >> 4)*16;
      #pragma unroll
      for (int mt = 0; mt < 4; ++mt){
        int rl = wr*64 + mt*16 + (l & 15);
        int off = (rl*128 + kb) ^ ((rl & 7) << 4);
        af[mt] = *(const bf16x8*)((const char*)Als + off);
      }
      #pragma unroll
      for (int nt = 0; nt < 4; ++nt){
        int cl2 = wc*64 + nt*16 + (l & 15);
        int off = (cl2*128 + kb) ^ ((cl2 & 7) << 4);
        bfr[nt] = *(const bf16x8*)((const char*)Bls + off);
      }
      #pragma unroll
      for (int mt = 0; mt < 4; ++mt)
        #pragma unroll
        for (int nt = 0; nt < 4; ++nt)
          acc[mt][nt] = __builtin_amdgcn_mfma_f32_16x16x32_bf16(af[mt], bfr[nt], acc[mt][nt], 0, 0, 0);
    }
  }
  #pragma unroll
  for (int mt = 0; mt < 4; ++mt){
    #pragma unroll
    for (int nt = 0; nt < 4; ++nt){
      int col = m0 + wc*64 + nt*16 + (l & 15);
      if (col >= HW) continue;
      int row0 = n0 + wr*64 + mt*16 + ((l >> 4) << 2);
      #pragma unroll
      for (int r = 0; r < 4; ++r){
        int row = row0 + r;
        if (row < HW) D[((size_t)b*HW + row)*HW + col] = -acc[mt][nt][r];
      }
    }
  }
}

// ---- 7b. top-9 selection: one wave per row; idx stored [k][b*HW+n] ----
__global__ __launch_bounds__(256) void k_select(const float* __restrict__ D, int* __restrict__ idxo){
  int wid = threadIdx.x >> 6, lane = threadIdx.x & 63;
  int row = blockIdx.x * 4 + wid;            // [0, B*HW)
  const float* Dr = D + (size_t)row * HW;
  float dvv[13]; int mvv[13];
  #pragma unroll
  for (int i = 0; i < 13; ++i){
    int m = lane + 64*i;
    dvv[i] = (m < HW) ? Dr[m] : 3.4e38f;
    mvv[i] = m;
  }
  for (int k = 0; k < KK; ++k){
    float bd = dvv[0]; int bi = 0;
    #pragma unroll
    for (int i = 1; i < 13; ++i) if (dvv[i] < bd){ bd = dvv[i]; bi = i; }
    unsigned long long key = ((unsigned long long)f2ord(bd) << 32) | (unsigned)mvv[bi];
    for (int off = 32; off; off >>= 1){
      unsigned long long o = __shfl_xor(key, off);
      if (o < key) key = o;
    }
    int wm = (int)(unsigned)(key & 0xffffffffu);
    if (lane == 0) idxo[(size_t)k*(Bb*HW) + row] = wm;
    if (mvv[bi] == wm) dvv[bi] = 3.4e38f;
  }
}

// ---- 8a. build combined weight [w1e-w2e ; w2e] (768 x 192), split bf16 hi/lo ----
__global__ void k_wp(const float* __restrict__ we, unsigned short* __restrict__ Wph,
                     unsigned short* __restrict__ Wpl){
  int i = blockIdx.x*256 + threadIdx.x;
  if (i >= 768*Cc) return;
  int o = i / Cc, c = i % Cc;
  float v = (o < CO) ? (we[(size_t)o*384 + c] - we[(size_t)o*384 + Cc + c])
                     : we[(size_t)(o - CO)*384 + Cc + c];
  unsigned short h = b16rne(v);
  float lo = v - __uint_as_float((unsigned)h << 16);
  Wph[i] = h;
  Wpl[i] = b16rne(lo);
}

// ---- 8b. PQ[b][o][n] = sum_c Wp[o][c]*xatt[n][c] via split-bf16 MFMA ----
__global__ __launch_bounds__(256) void k_gemm2(const unsigned short* __restrict__ Wph,
                                               const unsigned short* __restrict__ Wpl,
                                               const unsigned short* __restrict__ XAh,
                                               const unsigned short* __restrict__ XAl,
                                               float* __restrict__ PQ){
  int b = blockIdx.z;
  int o0 = blockIdx.y*128, n0 = blockIdx.x*128;
  __shared__ unsigned short Als[8192];
  __shared__ unsigned short Bls[8192];
  int t = threadIdx.x, w = t >> 6, l = t & 63;
  int wr = w >> 1, wc = w & 1;
  f32x4 acc[4][4] = {};
  int nn = t >> 1, half = t & 1;
  size_t bx = (size_t)b*HW*Cc;
  int ra = o0 + nn;
  int rb = n0 + nn; if (rb > HW-1) rb = HW-1;

  for (int cc = 0; cc < 9; ++cc){
    int seg = cc/3, kc0 = (cc%3)*64;
    const unsigned short* As_ = (seg < 2 ? Wph : Wpl);
    const unsigned short* Bs_ = (seg == 1 ? XAl : XAh) + bx;
    const uint4* ga = (const uint4*)(As_ + (size_t)ra*Cc + kc0 + half*32);
    const uint4* gb = (const uint4*)(Bs_ + (size_t)rb*Cc + kc0 + half*32);
    uint4 va0 = ga[0], va1 = ga[1], va2 = ga[2], va3 = ga[3];
    uint4 vb0 = gb[0], vb1 = gb[1], vb2 = gb[2], vb3 = gb[3];
    __syncthreads();
    int base = nn*128 + half*64;
    int sw = (nn & 7) << 4;
    *(uint4*)((char*)Als + ((base      ) ^ sw)) = va0;
    *(uint4*)((char*)Als + ((base + 16 ) ^ sw)) = va1;
    *(uint4*)((char*)Als + ((base + 32 ) ^ sw)) = va2;
    *(uint4*)((char*)Als + ((base + 48 ) ^ sw)) = va3;
    *(uint4*)((char*)Bls + ((base      ) ^ sw)) = vb0;
    *(uint4*)((char*)Bls + ((base + 16 ) ^ sw)) = vb1;
    *(uint4*)((char*)Bls + ((base + 32 ) ^ sw)) = vb2;
    *(uint4*)((char*)Bls + ((base + 48 ) ^ sw)) = vb3;
    __syncthreads();
    #pragma unroll
    for (int ks = 0; ks < 2; ++ks){
      bf16x8 af[4], bfr[4];
      int kb = ks*64 + (l >> 4)*16;
      #pragma unroll
      for (int mt = 0; mt < 4; ++mt){
        int rl = wr*64 + mt*16 + (l & 15);
        int off = (rl*128 + kb) ^ ((rl & 7) << 4);
        af[mt] = *(const bf16x8*)((const char*)Als + off);
      }
      #pragma unroll
      for (int nt = 0; nt < 4; ++nt){
        int cl2 = wc*64 + nt*16 + (l & 15);
        int off = (cl2*128 + kb) ^ ((cl2 & 7) << 4);
        bfr[nt] = *(const bf16x8*)((const char*)Bls + off);
      }
      #pragma unroll
      for (int mt = 0; mt < 4; ++mt)
        #pragma unroll
        for (int nt = 0; nt < 4; ++nt)
          acc[mt][nt] = __builtin_amdgcn_mfma_f32_16x16x32_bf16(af[mt], bfr[nt], acc[mt][nt], 0, 0, 0);
    }
  }
  #pragma unroll
  for (int mt = 0; mt < 4; ++mt){
    #pragma unroll
    for (int nt = 0; nt < 4; ++nt){
      int col = n0 + wc*64 + nt*16 + (l & 15);
      if (col >= HW) continue;
      int row0 = o0 + wr*64 + mt*16 + ((l >> 4) << 2);
      #pragma unroll
      for (int r = 0; r < 4; ++r){
        PQ[((size_t)b*768 + row0 + r)*HW + col] = acc[mt][nt][r];
      }
    }
  }
}

// ---- 9. epilogue: Q rows staged in LDS; coalesced idx; amortized over 8 o ----
__global__ __launch_bounds__(256) void k_edge(const float* __restrict__ PQ, const int* __restrict__ idx,
                                              const float* __restrict__ be, float* __restrict__ out){
  int bid = blockIdx.x;
  int b = bid / (CO/OG), og = bid % (CO/OG);
  int o0 = og * OG;
  __shared__ float Qls[OG][HW + 4];
  const float* Qbase = PQ + ((size_t)b*768 + CO + o0)*HW;
  int t = threadIdx.x;
  #pragma unroll
  for (int oo = 0; oo < OG; ++oo){
    if (t < 196) *(float4*)&Qls[oo][t*4] = *(const float4*)(Qbase + (size_t)oo*HW + t*4);
  }
  __syncthreads();
  const float* Pbase = PQ + ((size_t)b*768 + o0)*HW;
  float bev[OG];
  #pragma unroll
  for (int oo = 0; oo < OG; ++oo) bev[oo] = be[o0 + oo];
  for (int n = t; n < HW; n += 256){
    int ip[KK];
    #pragma unroll
    for (int k = 0; k < KK; ++k) ip[k] = idx[(size_t)k*(Bb*HW) + b*HW + n];
    float qm[OG];
    #pragma unroll
    for (int oo = 0; oo < OG; ++oo) qm[oo] = -3.4e38f;
    #pragma unroll
    for (int k = 0; k < KK; ++k){
      int j = ip[k];
      #pragma unroll
      for (int oo = 0; oo < OG; ++oo) qm[oo] = fmaxf(qm[oo], Qls[oo][j]);
    }
    #pragma unroll
    for (int oo = 0; oo < OG; ++oo){
      out[((size_t)b*CO + o0 + oo)*HW + n] = fmaxf(Pbase[(size_t)oo*HW + n] + bev[oo] + qm[oo], 0.f);
    }
  }
}

extern "C" void kernel_launch(void* const* d_in, const int* in_sizes, int n_in,
                              void* d_out, int out_size, void* d_ws, size_t ws_size,
                              hipStream_t stream){
  const float* x   = (const float*)d_in[0];
  const float* we  = (const float*)d_in[1];
  const float* be  = (const float*)d_in[2];
  const float* w1  = (const float*)d_in[3];
  const float* b1  = (const float*)d_in[4];
  const float* w2  = (const float*)d_in[5];
  const float* b2  = (const float*)d_in[6];
  const float* wsp = (const float*)d_in[7];
  const float* bsp = (const float*)d_in[8];
  float* out = (float*)d_out;

  // workspace layout (~60 MiB of the 256 MiB ws)
  float* ws    = (float*)d_ws;
  float* chm   = ws;                     // 3072
  float* chx   = chm + 3072;             // 3072
  float* chv   = chx + 3072;             // 3072
  float* vmaxA = chv + 3072;             // 3072
  float* invA  = vmaxA + 3072;           // 3072
  float* amean = invA + 3072;            // 12544
  float* amax  = amean + 12544;          // 12544
  float* satt  = amax + 12544;           // 12544
  float* nrm   = satt + 12544;           // 12544
  unsigned short* Wph = (unsigned short*)(nrm + 12544);    // 147456 ushorts
  unsigned short* Wpl = Wph + 147456;                      // 147456 ushorts
  unsigned short* Xnh = Wpl + 147456;    // 2408448 ushorts
  unsigned short* Xnl = Xnh + 2408448;   // 2408448 ushorts
  unsigned short* XAh = Xnl + 2408448;   // 2408448 ushorts
  unsigned short* XAl = XAh + 2408448;   // 2408448 ushorts
  int*   idx   = (int*)(XAl + 2408448);  // 112896 ints, layout [k][b*HW+n]
  float* D     = (float*)(idx + 112896); // 9834496 floats (aliased with PQ)
  float* PQ    = D;                      // written after D consumed by k_select

  k_chstats<<<768, 256, 0, stream>>>(x, chm, chx);
  k_mlp<<<16, 192, 0, stream>>>(chm, chx, w1, b1, w2, b2, chv);
  k_spin<<<64, 256, 0, stream>>>(x, chv, amean, amax, nrm);
  k_conv<<<64, 256, 0, stream>>>(amean, amax, wsp, bsp, satt);
  k_attstats<<<768, 256, 0, stream>>>(x, chv, satt, vmaxA, invA);
  k_cvt2<<<dim3(13, 3, 16), 256, 0, stream>>>(x, nrm, chv, satt, vmaxA, invA, Xnh, Xnl, XAh, XAl);
  k_gram<<<dim3(7, 7, 16), 256, 0, stream>>>(Xnh, Xnl, D);
  k_select<<<3136, 256, 0, stream>>>(D, idx);          // consume D before PQ overwrite
  k_wp<<<576, 256, 0, stream>>>(we, Wph, Wpl);
  k_gemm2<<<dim3(7, 6, 16), 256, 0, stream>>>(Wph, Wpl, XAh, XAl, PQ);
  k_edge<<<Bb*(CO/OG), 256, 0, stream>>>(PQ, idx, be, out);
}

// Round 9
// 145.989 us; speedup vs baseline: 2.1692x; 1.0909x over previous
//
#include <hip/hip_runtime.h>
#include <math.h>

#define HW 784
#define Cc 192
#define Bb 16
#define CO 384
#define KK 9
#define OG 8

typedef __attribute__((ext_vector_type(8))) short bf16x8;
typedef __attribute__((ext_vector_type(4))) float f32x4;

__device__ __forceinline__ unsigned f2ord(float f){
  unsigned u = __float_as_uint(f);
  return (u & 0x80000000u) ? ~u : (u | 0x80000000u);
}

__device__ __forceinline__ unsigned short b16rne(float v){
  unsigned u = __float_as_uint(v);
  unsigned r = u + 0x7FFFu + ((u >> 16) & 1u);
  return (unsigned short)(r >> 16);
}

// ---- 1. per-(b,c) mean & max over HW (float4 rows) ----
__global__ void k_chstats(const float* __restrict__ x, float* __restrict__ chm, float* __restrict__ chx){
  int wid = threadIdx.x >> 6, lane = threadIdx.x & 63;
  int r = blockIdx.x * 4 + wid;               // r in [0, B*C)
  const float4* row = (const float4*)(x + (size_t)r * HW);   // 196 float4s
  float s = 0.f, m = -3.4e38f;
  #pragma unroll
  for (int i = 0; i < 4; ++i){
    int f4 = lane + 64*i;
    if (f4 < 196){
      float4 v = row[f4];
      s += v.x + v.y + v.z + v.w;
      m = fmaxf(m, fmaxf(fmaxf(v.x, v.y), fmaxf(v.z, v.w)));
    }
  }
  for (int off = 32; off; off >>= 1){ s += __shfl_xor(s, off); m = fmaxf(m, __shfl_xor(m, off)); }
  if (lane == 0){ chm[r] = s / (float)HW; chx[r] = m; }
}

// ---- 2. channel-attention MLP: ch = sigmoid(mlp(mean)+mlp(max)) ----
__global__ void k_mlp(const float* __restrict__ chm, const float* __restrict__ chx,
                      const float* __restrict__ w1, const float* __restrict__ b1,
                      const float* __restrict__ w2, const float* __restrict__ b2,
                      float* __restrict__ chv){
  int b = blockIdx.x, t = threadIdx.x;
  __shared__ float vm[Cc], vx[Cc], hp[2][12];
  if (t < Cc){ vm[t] = chm[b*Cc + t]; vx[t] = chx[b*Cc + t]; }
  __syncthreads();
  if (t < 24){
    int h = t % 12;
    const float* src = (t < 12) ? vm : vx;
    float a = b1[h];
    for (int c = 0; c < Cc; ++c) a += src[c] * w1[h*Cc + c];
    hp[t/12][h] = fmaxf(a, 0.f);
  }
  __syncthreads();
  if (t < Cc){
    float a = 2.f * b2[t];
    for (int h = 0; h < 12; ++h) a += (hp[0][h] + hp[1][h]) * w2[t*12 + h];
    chv[b*Cc + t] = 1.f / (1.f + expf(-a));
  }
}

// ---- 3. spatial mean/max over C of x*ch  +  column norms of x (fused) ----
__global__ void k_spin(const float* __restrict__ x, const float* __restrict__ chv,
                       float* __restrict__ amean, float* __restrict__ amax,
                       float* __restrict__ nrm){
  int b = blockIdx.x >> 2;
  int n = ((blockIdx.x & 3) << 8) + threadIdx.x;
  if (n >= HW) return;
  const float* xb = x + (size_t)b*Cc*HW + n;
  const float* cb = chv + b*Cc;
  float s = 0.f, m = -3.4e38f, sq = 0.f;
  for (int c = 0; c < Cc; ++c){
    float xv = xb[(size_t)c*HW];
    float v = xv * cb[c];
    s += v; m = fmaxf(m, v); sq += xv*xv;
  }
  amean[b*HW + n] = s / (float)Cc;
  amax[b*HW + n]  = m;
  nrm[b*HW + n]   = fmaxf(sqrtf(sq), 1e-12f);
}

// ---- 4. 7x7 conv (2 in-ch) + sigmoid ----
__global__ void k_conv(const float* __restrict__ amean, const float* __restrict__ amax,
                       const float* __restrict__ wsp, const float* __restrict__ bsp,
                       float* __restrict__ satt){
  int b = blockIdx.x >> 2;
  int n = ((blockIdx.x & 3) << 8) + threadIdx.x;
  if (n >= HW) return;
  int yy = n / 28, xx = n % 28;
  float a = 0.f;
  for (int ky = 0; ky < 7; ++ky){
    int iy = yy + ky - 3; if (iy < 0 || iy >= 28) continue;
    for (int kx = 0; kx < 7; ++kx){
      int ix = xx + kx - 3; if (ix < 0 || ix >= 28) continue;
      int ii = b*HW + iy*28 + ix;
      a += amean[ii]*wsp[ky*7 + kx] + amax[ii]*wsp[49 + ky*7 + kx];
    }
  }
  satt[b*HW + n] = 1.f / (1.f + expf(-(a + bsp[0])));
}

// ---- 5. attention softmax stats per (b,c): vmax and inv = 1/(1+EPS*S)  (float4 rows) ----
__global__ void k_attstats(const float* __restrict__ x, const float* __restrict__ chv,
                           const float* __restrict__ satt,
                           float* __restrict__ vmaxA, float* __restrict__ invA){
  int wid = threadIdx.x >> 6, lane = threadIdx.x & 63;
  int r = blockIdx.x * 4 + wid;               // b*Cc + c
  int b = r / Cc;
  const float4* row = (const float4*)(x + (size_t)r * HW);
  const float4* sr  = (const float4*)(satt + b * HW);
  float ch = chv[r];
  float4 vv[4];
  float m = -3.4e38f;
  #pragma unroll
  for (int i = 0; i < 4; ++i){
    int f4 = lane + 64*i;
    if (f4 < 196){
      float4 xv = row[f4], sv = sr[f4];
      vv[i].x = (xv.x * ch) * sv.x; vv[i].y = (xv.y * ch) * sv.y;
      vv[i].z = (xv.z * ch) * sv.z; vv[i].w = (xv.w * ch) * sv.w;
      m = fmaxf(m, fmaxf(fmaxf(vv[i].x, vv[i].y), fmaxf(vv[i].z, vv[i].w)));
    }
  }
  for (int off = 32; off; off >>= 1) m = fmaxf(m, __shfl_xor(m, off));
  float s = 0.f;
  #pragma unroll
  for (int i = 0; i < 4; ++i){
    int f4 = lane + 64*i;
    if (f4 < 196){
      s += expf(vv[i].x - m) + expf(vv[i].y - m) + expf(vv[i].z - m) + expf(vv[i].w - m);
    }
  }
  for (int off = 32; off; off >>= 1) s += __shfl_xor(s, off);
  if (lane == 0){ vmaxA[r] = m; invA[r] = 1.f / (1.f + 1e-10f * s); }
}

// ---- 6. merged: transpose+split pass (blocks 0..623)  |  weight prep (blocks 624..1199) ----
__global__ __launch_bounds__(256) void k_cvt2wp(const float* __restrict__ x, const float* __restrict__ nrm,
                                                const float* __restrict__ chv, const float* __restrict__ satt,
                                                const float* __restrict__ vmaxA, const float* __restrict__ invA,
                                                const float* __restrict__ we,
                                                unsigned short* __restrict__ Xnh, unsigned short* __restrict__ Xnl,
                                                unsigned short* __restrict__ XAh, unsigned short* __restrict__ XAl,
                                                unsigned short* __restrict__ Wph, unsigned short* __restrict__ Wpl){
  int bid = blockIdx.x, t = threadIdx.x;
  if (bid >= 624){                         // ---- weight prep path ----
    int i = (bid - 624)*256 + t;           // < 147456 exactly
    int o = i / Cc, c = i % Cc;
    float v = (o < CO) ? (we[(size_t)o*384 + c] - we[(size_t)o*384 + Cc + c])
                       : we[(size_t)(o - CO)*384 + Cc + c];
    unsigned short h = b16rne(v);
    float lo = v - __uint_as_float((unsigned)h << 16);
    Wph[i] = h;
    Wpl[i] = b16rne(lo);
    return;
  }
  // ---- transpose + split path ----
  int xx = bid % 13, yy = (bid / 13) % 3, b = bid / 39;
  int c0 = yy*64, n0 = xx*64;
  __shared__ float T[64][65];
  __shared__ float chs[64], vms[64], ivs[64];
  int nl = (t & 15) * 4, cl = t >> 4;
  const float* xb = x + (size_t)b*Cc*HW;
  #pragma unroll
  for (int r = 0; r < 4; ++r){
    int c_loc = cl + r*16;
    int n = n0 + nl;
    float4 v = (n < HW) ? *(const float4*)(xb + (size_t)(c0 + c_loc)*HW + n) : make_float4(0,0,0,0);
    *(float4*)&T[c_loc][nl] = v;
  }
  if (t < 64){
    chs[t] = chv[b*Cc + c0 + t];
    vms[t] = vmaxA[b*Cc + c0 + t];
    ivs[t] = invA[b*Cc + c0 + t];
  }
  __syncthreads();
  int nr = t >> 2, q = t & 3;
  int n_g = n0 + nr;
  if (n_g >= HW) return;
  float nv = nrm[b*HW + n_g];
  float sr = satt[b*HW + n_g];
  unsigned int nh[8], nlw[8], ah[8], al[8];
  #pragma unroll
  for (int j = 0; j < 8; ++j){
    unsigned int parts[2][2];
    #pragma unroll
    for (int e = 0; e < 2; ++e){
      int cc_ = q*16 + 2*j + e;
      float v = T[cc_][nr];
      float xnv = v / nv;
      unsigned short h0 = b16rne(xnv);
      float l0 = xnv - __uint_as_float((unsigned)h0 << 16);
      parts[0][e] = (unsigned)h0 | ((unsigned)b16rne(l0) << 16);
      float vvv = (v * chs[cc_]) * sr;
      float ex = expf(vvv - vms[cc_]);
      float a = ex * ivs[cc_];
      float xav = v * ((2.f*a - 1.f)*0.025f + 1.f);
      unsigned short h1 = b16rne(xav);
      float l1 = xav - __uint_as_float((unsigned)h1 << 16);
      parts[1][e] = (unsigned)h1 | ((unsigned)b16rne(l1) << 16);
    }
    nh[j]  = (parts[0][0] & 0xFFFFu) | (parts[0][1] << 16);
    nlw[j] = (parts[0][0] >> 16)     | (parts[0][1] & 0xFFFF0000u);
    ah[j]  = (parts[1][0] & 0xFFFFu) | (parts[1][1] << 16);
    al[j]  = (parts[1][0] >> 16)     | (parts[1][1] & 0xFFFF0000u);
  }
  size_t base = ((size_t)b*HW + n_g)*Cc + c0 + q*16;
  *(uint4*)(Xnh + base)     = make_uint4(nh[0], nh[1], nh[2], nh[3]);
  *(uint4*)(Xnh + base + 8) = make_uint4(nh[4], nh[5], nh[6], nh[7]);
  *(uint4*)(Xnl + base)     = make_uint4(nlw[0], nlw[1], nlw[2], nlw[3]);
  *(uint4*)(Xnl + base + 8) = make_uint4(nlw[4], nlw[5], nlw[6], nlw[7]);
  *(uint4*)(XAh + base)     = make_uint4(ah[0], ah[1], ah[2], ah[3]);
  *(uint4*)(XAh + base + 8) = make_uint4(ah[4], ah[5], ah[6], ah[7]);
  *(uint4*)(XAl + base)     = make_uint4(al[0], al[1], al[2], al[3]);
  *(uint4*)(XAl + base + 8) = make_uint4(al[4], al[5], al[6], al[7]);
}

// ---- 7. merged MFMA launch: blocks 0..783 = Gram (D), 784..1455 = GEMM (PQ).
//      Both use the verified split-bf16 MFMA 128x128 tile. ----
__global__ __launch_bounds__(256) void k_gramgemm(const unsigned short* __restrict__ Xnh,
                                                  const unsigned short* __restrict__ Xnl,
                                                  const unsigned short* __restrict__ Wph,
                                                  const unsigned short* __restrict__ Wpl,
                                                  const unsigned short* __restrict__ XAh,
                                                  const unsigned short* __restrict__ XAl,
                                                  float* __restrict__ D, float* __restrict__ PQ){
  __shared__ unsigned short Als[8192];
  __shared__ unsigned short Bls[8192];
  int bid = blockIdx.x;
  int t = threadIdx.x, w = t >> 6, l = t & 63;
  int wr = w >> 1, wc = w & 1;
  f32x4 acc[4][4] = {};
  int nn = t >> 1, half = t & 1;

  bool isGram = bid < 784;
  int b, r0, c0;                 // r0 = A-side tile base, c0 = B-side tile base
  const unsigned short *A_h, *A_l, *B_h, *B_l;
  if (isGram){
    b = bid / 49; int rem = bid % 49;
    c0 = (rem % 7) * 128; r0 = (rem / 7) * 128;
    size_t bb = (size_t)b*HW*Cc;
    A_h = Xnh + bb; A_l = Xnl + bb; B_h = Xnh + bb; B_l = Xnl + bb;
  } else {
    int id = bid - 784;
    b = id / 42; int rem = id % 42;
    c0 = (rem % 7) * 128; r0 = (rem / 7) * 128;
    size_t bb = (size_t)b*HW*Cc;
    A_h = Wph; A_l = Wpl; B_h = XAh + bb; B_l = XAl + bb;
  }
  int ra = r0 + nn; if (isGram && ra > HW-1) ra = HW-1;
  int rb = c0 + nn; if (rb > HW-1) rb = HW-1;

  for (int cc = 0; cc < 9; ++cc){
    int seg = cc/3, kc0 = (cc%3)*64;
    const unsigned short* As_ = (seg < 2 ? A_h : A_l);
    const unsigned short* Bs_ = (seg == 1 ? B_l : B_h);
    const uint4* ga = (const uint4*)(As_ + (size_t)ra*Cc + kc0 + half*32);
    const uint4* gb = (const uint4*)(Bs_ + (size_t)rb*Cc + kc0 + half*32);
    uint4 va0 = ga[0], va1 = ga[1], va2 = ga[2], va3 = ga[3];
    uint4 vb0 = gb[0], vb1 = gb[1], vb2 = gb[2], vb3 = gb[3];
    __syncthreads();
    int base = nn*128 + half*64;
    int sw = (nn & 7) << 4;
    *(uint4*)((char*)Als + ((base      ) ^ sw)) = va0;
    *(uint4*)((char*)Als + ((base + 16 ) ^ sw)) = va1;
    *(uint4*)((char*)Als + ((base + 32 ) ^ sw)) = va2;
    *(uint4*)((char*)Als + ((base + 48 ) ^ sw)) = va3;
    *(uint4*)((char*)Bls + ((base      ) ^ sw)) = vb0;
    *(uint4*)((char*)Bls + ((base + 16 ) ^ sw)) = vb1;
    *(uint4*)((char*)Bls + ((base + 32 ) ^ sw)) = vb2;
    *(uint4*)((char*)Bls + ((base + 48 ) ^ sw)) = vb3;
    __syncthreads();
    #pragma unroll
    for (int ks = 0; ks < 2; ++ks){
      bf16x8 af[4], bfr[4];
      int kb = ks*64 + (l >> 4)*16;
      #pragma unroll
      for (int mt = 0; mt < 4; ++mt){
        int rl = wr*64 + mt*16 + (l & 15);
        int off = (rl*128 + kb) ^ ((rl & 7) << 4);
        af[mt] = *(const bf16x8*)((const char*)Als + off);
      }
      #pragma unroll
      for (int nt = 0; nt < 4; ++nt){
        int cl2 = wc*64 + nt*16 + (l & 15);
        int off = (cl2*128 + kb) ^ ((cl2 & 7) << 4);
        bfr[nt] = *(const bf16x8*)((const char*)Bls + off);
      }
      #pragma unroll
      for (int mt = 0; mt < 4; ++mt)
        #pragma unroll
        for (int nt = 0; nt < 4; ++nt)
          acc[mt][nt] = __builtin_amdgcn_mfma_f32_16x16x32_bf16(af[mt], bfr[nt], acc[mt][nt], 0, 0, 0);
    }
  }
  if (isGram){
    #pragma unroll
    for (int mt = 0; mt < 4; ++mt){
      #pragma unroll
      for (int nt = 0; nt < 4; ++nt){
        int col = c0 + wc*64 + nt*16 + (l & 15);
        if (col >= HW) continue;
        int row0 = r0 + wr*64 + mt*16 + ((l >> 4) << 2);
        #pragma unroll
        for (int r = 0; r < 4; ++r){
          int row = row0 + r;
          if (row < HW) D[((size_t)b*HW + row)*HW + col] = -acc[mt][nt][r];
        }
      }
    }
  } else {
    #pragma unroll
    for (int mt = 0; mt < 4; ++mt){
      #pragma unroll
      for (int nt = 0; nt < 4; ++nt){
        int col = c0 + wc*64 + nt*16 + (l & 15);
        if (col >= HW) continue;
        int row0 = r0 + wr*64 + mt*16 + ((l >> 4) << 2);
        #pragma unroll
        for (int r = 0; r < 4; ++r){
          PQ[((size_t)b*768 + row0 + r)*HW + col] = acc[mt][nt][r];
        }
      }
    }
  }
}

// ---- 8. top-9 selection: one wave per row; idx stored [k][b*HW+n] ----
__global__ __launch_bounds__(256) void k_select(const float* __restrict__ D, int* __restrict__ idxo){
  int wid = threadIdx.x >> 6, lane = threadIdx.x & 63;
  int row = blockIdx.x * 4 + wid;            // [0, B*HW)
  const float* Dr = D + (size_t)row * HW;
  float dvv[13]; int mvv[13];
  #pragma unroll
  for (int i = 0; i < 13; ++i){
    int m = lane + 64*i;
    dvv[i] = (m < HW) ? Dr[m] : 3.4e38f;
    mvv[i] = m;
  }
  for (int k = 0; k < KK; ++k){
    float bd = dvv[0]; int bi = 0;
    #pragma unroll
    for (int i = 1; i < 13; ++i) if (dvv[i] < bd){ bd = dvv[i]; bi = i; }
    unsigned long long key = ((unsigned long long)f2ord(bd) << 32) | (unsigned)mvv[bi];
    for (int off = 32; off; off >>= 1){
      unsigned long long o = __shfl_xor(key, off);
      if (o < key) key = o;
    }
    int wm = (int)(unsigned)(key & 0xffffffffu);
    if (lane == 0) idxo[(size_t)k*(Bb*HW) + row] = wm;
    if (mvv[bi] == wm) dvv[bi] = 3.4e38f;
  }
}

// ---- 9. epilogue: Q rows staged in LDS; coalesced idx; amortized over 8 o ----
__global__ __launch_bounds__(256) void k_edge(const float* __restrict__ PQ, const int* __restrict__ idx,
                                              const float* __restrict__ be, float* __restrict__ out){
  int bid = blockIdx.x;
  int b = bid / (CO/OG), og = bid % (CO/OG);
  int o0 = og * OG;
  __shared__ float Qls[OG][HW + 4];
  const float* Qbase = PQ + ((size_t)b*768 + CO + o0)*HW;
  int t = threadIdx.x;
  #pragma unroll
  for (int oo = 0; oo < OG; ++oo){
    if (t < 196) *(float4*)&Qls[oo][t*4] = *(const float4*)(Qbase + (size_t)oo*HW + t*4);
  }
  __syncthreads();
  const float* Pbase = PQ + ((size_t)b*768 + o0)*HW;
  float bev[OG];
  #pragma unroll
  for (int oo = 0; oo < OG; ++oo) bev[oo] = be[o0 + oo];
  for (int n = t; n < HW; n += 256){
    int ip[KK];
    #pragma unroll
    for (int k = 0; k < KK; ++k) ip[k] = idx[(size_t)k*(Bb*HW) + b*HW + n];
    float qm[OG];
    #pragma unroll
    for (int oo = 0; oo < OG; ++oo) qm[oo] = -3.4e38f;
    #pragma unroll
    for (int k = 0; k < KK; ++k){
      int j = ip[k];
      #pragma unroll
      for (int oo = 0; oo < OG; ++oo) qm[oo] = fmaxf(qm[oo], Qls[oo][j]);
    }
    #pragma unroll
    for (int oo = 0; oo < OG; ++oo){
      out[((size_t)b*CO + o0 + oo)*HW + n] = fmaxf(Pbase[(size_t)oo*HW + n] + bev[oo] + qm[oo], 0.f);
    }
  }
}

extern "C" void kernel_launch(void* const* d_in, const int* in_sizes, int n_in,
                              void* d_out, int out_size, void* d_ws, size_t ws_size,
                              hipStream_t stream){
  const float* x   = (const float*)d_in[0];
  const float* we  = (const float*)d_in[1];
  const float* be  = (const float*)d_in[2];
  const float* w1  = (const float*)d_in[3];
  const float* b1  = (const float*)d_in[4];
  const float* w2  = (const float*)d_in[5];
  const float* b2  = (const float*)d_in[6];
  const float* wsp = (const float*)d_in[7];
  const float* bsp = (const float*)d_in[8];
  float* out = (float*)d_out;

  // workspace layout (~99 MiB of 256 MiB ws) — D and PQ now SEPARATE buffers
  float* ws    = (float*)d_ws;
  float* chm   = ws;                     // 3072
  float* chx   = chm + 3072;             // 3072
  float* chv   = chx + 3072;             // 3072
  float* vmaxA = chv + 3072;             // 3072
  float* invA  = vmaxA + 3072;           // 3072
  float* amean = invA + 3072;            // 12544
  float* amax  = amean + 12544;          // 12544
  float* satt  = amax + 12544;           // 12544
  float* nrm   = satt + 12544;           // 12544
  unsigned short* Wph = (unsigned short*)(nrm + 12544);    // 147456 ushorts
  unsigned short* Wpl = Wph + 147456;                      // 147456 ushorts
  unsigned short* Xnh = Wpl + 147456;    // 2408448 ushorts
  unsigned short* Xnl = Xnh + 2408448;   // 2408448 ushorts
  unsigned short* XAh = Xnl + 2408448;   // 2408448 ushorts
  unsigned short* XAl = XAh + 2408448;   // 2408448 ushorts
  int*   idx   = (int*)(XAl + 2408448);  // 112896 ints, layout [k][b*HW+n]
  float* D     = (float*)(idx + 112896); // 9834496 floats
  float* PQ    = D + 9834496;            // 9633792 floats (independent)

  k_chstats<<<768, 256, 0, stream>>>(x, chm, chx);
  k_mlp<<<16, 192, 0, stream>>>(chm, chx, w1, b1, w2, b2, chv);
  k_spin<<<64, 256, 0, stream>>>(x, chv, amean, amax, nrm);
  k_conv<<<64, 256, 0, stream>>>(amean, amax, wsp, bsp, satt);
  k_attstats<<<768, 256, 0, stream>>>(x, chv, satt, vmaxA, invA);
  k_cvt2wp<<<1200, 256, 0, stream>>>(x, nrm, chv, satt, vmaxA, invA, we,
                                     Xnh, Xnl, XAh, XAl, Wph, Wpl);
  k_gramgemm<<<1456, 256, 0, stream>>>(Xnh, Xnl, Wph, Wpl, XAh, XAl, D, PQ);
  k_select<<<3136, 256, 0, stream>>>(D, idx);
  k_edge<<<Bb*(CO/OG), 256, 0, stream>>>(PQ, idx, be, out);
}

// Round 11
// 142.634 us; speedup vs baseline: 2.2202x; 1.0235x over previous
//
#include <hip/hip_runtime.h>
#include <math.h>

#define HW 784
#define Cc 192
#define Bb 16
#define CO 384
#define KK 9
#define OG 8

typedef __attribute__((ext_vector_type(8))) short bf16x8;
typedef __attribute__((ext_vector_type(4))) float f32x4;

__device__ __forceinline__ unsigned f2ord(float f){
  unsigned u = __float_as_uint(f);
  return (u & 0x80000000u) ? ~u : (u | 0x80000000u);
}

__device__ __forceinline__ unsigned short b16rne(float v){
  unsigned u = __float_as_uint(v);
  unsigned r = u + 0x7FFFu + ((u >> 16) & 1u);
  return (unsigned short)(r >> 16);
}

// ---- 1. per-(b,c) mean & max over HW (float4 rows) ----
__global__ void k_chstats(const float* __restrict__ x, float* __restrict__ chm, float* __restrict__ chx){
  int wid = threadIdx.x >> 6, lane = threadIdx.x & 63;
  int r = blockIdx.x * 4 + wid;               // r in [0, B*C)
  const float4* row = (const float4*)(x + (size_t)r * HW);   // 196 float4s
  float s = 0.f, m = -3.4e38f;
  #pragma unroll
  for (int i = 0; i < 4; ++i){
    int f4 = lane + 64*i;
    if (f4 < 196){
      float4 v = row[f4];
      s += v.x + v.y + v.z + v.w;
      m = fmaxf(m, fmaxf(fmaxf(v.x, v.y), fmaxf(v.z, v.w)));
    }
  }
  for (int off = 32; off; off >>= 1){ s += __shfl_xor(s, off); m = fmaxf(m, __shfl_xor(m, off)); }
  if (lane == 0){ chm[r] = s / (float)HW; chx[r] = m; }
}

// ---- 2. channel-attention MLP: ch = sigmoid(mlp(mean)+mlp(max)) ----
__global__ void k_mlp(const float* __restrict__ chm, const float* __restrict__ chx,
                      const float* __restrict__ w1, const float* __restrict__ b1,
                      const float* __restrict__ w2, const float* __restrict__ b2,
                      float* __restrict__ chv){
  int b = blockIdx.x, t = threadIdx.x;
  __shared__ float vm[Cc], vx[Cc], hp[2][12];
  if (t < Cc){ vm[t] = chm[b*Cc + t]; vx[t] = chx[b*Cc + t]; }
  __syncthreads();
  if (t < 24){
    int h = t % 12;
    const float* src = (t < 12) ? vm : vx;
    float a = b1[h];
    for (int c = 0; c < Cc; ++c) a += src[c] * w1[h*Cc + c];
    hp[t/12][h] = fmaxf(a, 0.f);
  }
  __syncthreads();
  if (t < Cc){
    float a = 2.f * b2[t];
    for (int h = 0; h < 12; ++h) a += (hp[0][h] + hp[1][h]) * w2[t*12 + h];
    chv[b*Cc + t] = 1.f / (1.f + expf(-a));
  }
}

// ---- 3. spatial mean/max over C of x*ch  +  column norms of x (fused) ----
__global__ void k_spin(const float* __restrict__ x, const float* __restrict__ chv,
                       float* __restrict__ amean, float* __restrict__ amax,
                       float* __restrict__ nrm){
  int b = blockIdx.x >> 2;
  int n = ((blockIdx.x & 3) << 8) + threadIdx.x;
  if (n >= HW) return;
  const float* xb = x + (size_t)b*Cc*HW + n;
  const float* cb = chv + b*Cc;
  float s = 0.f, m = -3.4e38f, sq = 0.f;
  for (int c = 0; c < Cc; ++c){
    float xv = xb[(size_t)c*HW];
    float v = xv * cb[c];
    s += v; m = fmaxf(m, v); sq += xv*xv;
  }
  amean[b*HW + n] = s / (float)Cc;
  amax[b*HW + n]  = m;
  nrm[b*HW + n]   = fmaxf(sqrtf(sq), 1e-12f);
}

// ---- 4. 7x7 conv (2 in-ch) + sigmoid ----
__global__ void k_conv(const float* __restrict__ amean, const float* __restrict__ amax,
                       const float* __restrict__ wsp, const float* __restrict__ bsp,
                       float* __restrict__ satt){
  int b = blockIdx.x >> 2;
  int n = ((blockIdx.x & 3) << 8) + threadIdx.x;
  if (n >= HW) return;
  int yy = n / 28, xx = n % 28;
  float a = 0.f;
  for (int ky = 0; ky < 7; ++ky){
    int iy = yy + ky - 3; if (iy < 0 || iy >= 28) continue;
    for (int kx = 0; kx < 7; ++kx){
      int ix = xx + kx - 3; if (ix < 0 || ix >= 28) continue;
      int ii = b*HW + iy*28 + ix;
      a += amean[ii]*wsp[ky*7 + kx] + amax[ii]*wsp[49 + ky*7 + kx];
    }
  }
  satt[b*HW + n] = 1.f / (1.f + expf(-(a + bsp[0])));
}

// ---- 5. attention softmax stats per (b,c): vmax and inv = 1/(1+EPS*S)  (float4 rows) ----
__global__ void k_attstats(const float* __restrict__ x, const float* __restrict__ chv,
                           const float* __restrict__ satt,
                           float* __restrict__ vmaxA, float* __restrict__ invA){
  int wid = threadIdx.x >> 6, lane = threadIdx.x & 63;
  int r = blockIdx.x * 4 + wid;               // b*Cc + c
  int b = r / Cc;
  const float4* row = (const float4*)(x + (size_t)r * HW);
  const float4* sr  = (const float4*)(satt + b * HW);
  float ch = chv[r];
  float4 vv[4];
  float m = -3.4e38f;
  #pragma unroll
  for (int i = 0; i < 4; ++i){
    int f4 = lane + 64*i;
    if (f4 < 196){
      float4 xv = row[f4], sv = sr[f4];
      vv[i].x = (xv.x * ch) * sv.x; vv[i].y = (xv.y * ch) * sv.y;
      vv[i].z = (xv.z * ch) * sv.z; vv[i].w = (xv.w * ch) * sv.w;
      m = fmaxf(m, fmaxf(fmaxf(vv[i].x, vv[i].y), fmaxf(vv[i].z, vv[i].w)));
    }
  }
  for (int off = 32; off; off >>= 1) m = fmaxf(m, __shfl_xor(m, off));
  float s = 0.f;
  #pragma unroll
  for (int i = 0; i < 4; ++i){
    int f4 = lane + 64*i;
    if (f4 < 196){
      s += expf(vv[i].x - m) + expf(vv[i].y - m) + expf(vv[i].z - m) + expf(vv[i].w - m);
    }
  }
  for (int off = 32; off; off >>= 1) s += __shfl_xor(s, off);
  if (lane == 0){ vmaxA[r] = m; invA[r] = 1.f / (1.f + 1e-10f * s); }
}

// ---- 6. merged: transpose+split pass (blocks 0..623)  |  weight prep (blocks 624..1199) ----
__global__ __launch_bounds__(256) void k_cvt2wp(const float* __restrict__ x, const float* __restrict__ nrm,
                                                const float* __restrict__ chv, const float* __restrict__ satt,
                                                const float* __restrict__ vmaxA, const float* __restrict__ invA,
                                                const float* __restrict__ we,
                                                unsigned short* __restrict__ Xnh, unsigned short* __restrict__ Xnl,
                                                unsigned short* __restrict__ XAh, unsigned short* __restrict__ XAl,
                                                unsigned short* __restrict__ Wph, unsigned short* __restrict__ Wpl){
  int bid = blockIdx.x, t = threadIdx.x;
  if (bid >= 624){                         // ---- weight prep path ----
    int i = (bid - 624)*256 + t;           // < 147456 exactly
    int o = i / Cc, c = i % Cc;
    float v = (o < CO) ? (we[(size_t)o*384 + c] - we[(size_t)o*384 + Cc + c])
                       : we[(size_t)(o - CO)*384 + Cc + c];
    unsigned short h = b16rne(v);
    float lo = v - __uint_as_float((unsigned)h << 16);
    Wph[i] = h;
    Wpl[i] = b16rne(lo);
    return;
  }
  // ---- transpose + split path ----
  int xx = bid % 13, yy = (bid / 13) % 3, b = bid / 39;
  int c0 = yy*64, n0 = xx*64;
  __shared__ float T[64][65];
  __shared__ float chs[64], vms[64], ivs[64];
  int nl = (t & 15) * 4, cl = t >> 4;
  const float* xb = x + (size_t)b*Cc*HW;
  #pragma unroll
  for (int r = 0; r < 4; ++r){
    int c_loc = cl + r*16;
    int n = n0 + nl;
    float4 v = (n < HW) ? *(const float4*)(xb + (size_t)(c0 + c_loc)*HW + n) : make_float4(0,0,0,0);
    *(float4*)&T[c_loc][nl] = v;
  }
  if (t < 64){
    chs[t] = chv[b*Cc + c0 + t];
    vms[t] = vmaxA[b*Cc + c0 + t];
    ivs[t] = invA[b*Cc + c0 + t];
  }
  __syncthreads();
  int nr = t >> 2, q = t & 3;
  int n_g = n0 + nr;
  if (n_g >= HW) return;
  float nv = nrm[b*HW + n_g];
  float sr = satt[b*HW + n_g];
  unsigned int nh[8], nlw[8], ah[8], al[8];
  #pragma unroll
  for (int j = 0; j < 8; ++j){
    unsigned int parts[2][2];
    #pragma unroll
    for (int e = 0; e < 2; ++e){
      int cc_ = q*16 + 2*j + e;
      float v = T[cc_][nr];
      float xnv = v / nv;
      unsigned short h0 = b16rne(xnv);
      float l0 = xnv - __uint_as_float((unsigned)h0 << 16);
      parts[0][e] = (unsigned)h0 | ((unsigned)b16rne(l0) << 16);
      float vvv = (v * chs[cc_]) * sr;
      float ex = expf(vvv - vms[cc_]);
      float a = ex * ivs[cc_];
      float xav = v * ((2.f*a - 1.f)*0.025f + 1.f);
      unsigned short h1 = b16rne(xav);
      float l1 = xav - __uint_as_float((unsigned)h1 << 16);
      parts[1][e] = (unsigned)h1 | ((unsigned)b16rne(l1) << 16);
    }
    nh[j]  = (parts[0][0] & 0xFFFFu) | (parts[0][1] << 16);
    nlw[j] = (parts[0][0] >> 16)     | (parts[0][1] & 0xFFFF0000u);
    ah[j]  = (parts[1][0] & 0xFFFFu) | (parts[1][1] << 16);
    al[j]  = (parts[1][0] >> 16)     | (parts[1][1] & 0xFFFF0000u);
  }
  size_t base = ((size_t)b*HW + n_g)*Cc + c0 + q*16;
  *(uint4*)(Xnh + base)     = make_uint4(nh[0], nh[1], nh[2], nh[3]);
  *(uint4*)(Xnh + base + 8) = make_uint4(nh[4], nh[5], nh[6], nh[7]);
  *(uint4*)(Xnl + base)     = make_uint4(nlw[0], nlw[1], nlw[2], nlw[3]);
  *(uint4*)(Xnl + base + 8) = make_uint4(nlw[4], nlw[5], nlw[6], nlw[7]);
  *(uint4*)(XAh + base)     = make_uint4(ah[0], ah[1], ah[2], ah[3]);
  *(uint4*)(XAh + base + 8) = make_uint4(ah[4], ah[5], ah[6], ah[7]);
  *(uint4*)(XAl + base)     = make_uint4(al[0], al[1], al[2], al[3]);
  *(uint4*)(XAl + base + 8) = make_uint4(al[4], al[5], al[6], al[7]);
}

// ---- 7. merged MFMA launch, XCD-swizzled, symmetric gram.
//      logical blocks: 0..447 = gram upper-tri tiles (mirror-write D^T),
//                      448..1119 = GEMM (PQ). 1120 = 8*140 exactly. ----
__global__ __launch_bounds__(256) void k_gramgemm(const unsigned short* __restrict__ Xnh,
                                                  const unsigned short* __restrict__ Xnl,
                                                  const unsigned short* __restrict__ Wph,
                                                  const unsigned short* __restrict__ Wpl,
                                                  const unsigned short* __restrict__ XAh,
                                                  const unsigned short* __restrict__ XAl,
                                                  float* __restrict__ D, float* __restrict__ PQ){
  __shared__ __align__(16) char smem[32768];
  unsigned short* Als = (unsigned short*)smem;          // 8192 ushorts
  unsigned short* Bls = Als + 8192;                     // 8192 ushorts
  float* Tt = (float*)smem;                             // mirror-transpose staging (16.5KB)

  int hwbid = blockIdx.x;
  int bid = (hwbid & 7) * 140 + (hwbid >> 3);           // XCD-chunk swizzle (bijective, 1120=8*140)
  int t = threadIdx.x, w = t >> 6, l = t & 63;
  int wr = w >> 1, wc = w & 1;
  f32x4 acc[4][4] = {};
  int nn = t >> 1, half = t & 1;

  bool isGram = bid < 448;
  int b, r0, c0, ty = 0, tx = 0;
  const unsigned short *A_h, *A_l, *B_h, *B_l;
  if (isGram){
    b = bid / 28; int rm = bid % 28;
    if      (rm <  7){ ty=0; tx=rm; }
    else if (rm < 13){ ty=1; tx=1+rm-7; }
    else if (rm < 18){ ty=2; tx=2+rm-13; }
    else if (rm < 22){ ty=3; tx=3+rm-18; }
    else if (rm < 25){ ty=4; tx=4+rm-22; }
    else if (rm < 27){ ty=5; tx=5+rm-25; }
    else             { ty=6; tx=6; }
    r0 = ty*128; c0 = tx*128;
    size_t bb = (size_t)b*HW*Cc;
    A_h = Xnh + bb; A_l = Xnl + bb; B_h = Xnh + bb; B_l = Xnl + bb;
  } else {
    int id = bid - 448;
    b = id / 42; int rem = id % 42;
    c0 = (rem % 7) * 128; r0 = (rem / 7) * 128;
    size_t bb = (size_t)b*HW*Cc;
    A_h = Wph; A_l = Wpl; B_h = XAh + bb; B_l = XAl + bb;
  }
  int ra = r0 + nn; if (isGram && ra > HW-1) ra = HW-1;
  int rb = c0 + nn; if (rb > HW-1) rb = HW-1;

  for (int cc = 0; cc < 9; ++cc){
    int seg = cc/3, kc0 = (cc%3)*64;
    const unsigned short* As_ = (seg < 2 ? A_h : A_l);
    const unsigned short* Bs_ = (seg == 1 ? B_l : B_h);
    const uint4* ga = (const uint4*)(As_ + (size_t)ra*Cc + kc0 + half*32);
    const uint4* gb = (const uint4*)(Bs_ + (size_t)rb*Cc + kc0 + half*32);
    uint4 va0 = ga[0], va1 = ga[1], va2 = ga[2], va3 = ga[3];
    uint4 vb0 = gb[0], vb1 = gb[1], vb2 = gb[2], vb3 = gb[3];
    __syncthreads();
    int base = nn*128 + half*64;
    int sw = (nn & 7) << 4;
    *(uint4*)((char*)Als + ((base      ) ^ sw)) = va0;
    *(uint4*)((char*)Als + ((base + 16 ) ^ sw)) = va1;
    *(uint4*)((char*)Als + ((base + 32 ) ^ sw)) = va2;
    *(uint4*)((char*)Als + ((base + 48 ) ^ sw)) = va3;
    *(uint4*)((char*)Bls + ((base      ) ^ sw)) = vb0;
    *(uint4*)((char*)Bls + ((base + 16 ) ^ sw)) = vb1;
    *(uint4*)((char*)Bls + ((base + 32 ) ^ sw)) = vb2;
    *(uint4*)((char*)Bls + ((base + 48 ) ^ sw)) = vb3;
    __syncthreads();
    #pragma unroll
    for (int ks = 0; ks < 2; ++ks){
      bf16x8 af[4], bfr[4];
      int kb = ks*64 + (l >> 4)*16;
      #pragma unroll
      for (int mt = 0; mt < 4; ++mt){
        int rl = wr*64 + mt*16 + (l & 15);
        int off = (rl*128 + kb) ^ ((rl & 7) << 4);
        af[mt] = *(const bf16x8*)((const char*)Als + off);
      }
      #pragma unroll
      for (int nt = 0; nt < 4; ++nt){
        int cl2 = wc*64 + nt*16 + (l & 15);
        int off = (cl2*128 + kb) ^ ((cl2 & 7) << 4);
        bfr[nt] = *(const bf16x8*)((const char*)Bls + off);
      }
      #pragma unroll
      for (int mt = 0; mt < 4; ++mt)
        #pragma unroll
        for (int nt = 0; nt < 4; ++nt)
          acc[mt][nt] = __builtin_amdgcn_mfma_f32_16x16x32_bf16(af[mt], bfr[nt], acc[mt][nt], 0, 0, 0);
    }
  }
  if (isGram){
    // normal write: D[r0+row][c0+col] = -acc
    #pragma unroll
    for (int mt = 0; mt < 4; ++mt){
      #pragma unroll
      for (int nt = 0; nt < 4; ++nt){
        int col = c0 + wc*64 + nt*16 + (l & 15);
        if (col >= HW) continue;
        int row0 = r0 + wr*64 + mt*16 + ((l >> 4) << 2);
        #pragma unroll
        for (int r = 0; r < 4; ++r){
          int row = row0 + r;
          if (row < HW) D[((size_t)b*HW + row)*HW + col] = -acc[mt][nt][r];
        }
      }
    }
    if (tx > ty){
      // mirror write: D[c0+col][r0+row] = -acc (transposed), LDS-staged per nt quarter.
      // rows r0..r0+127 always < HW here (ty <= 5).
      #pragma unroll
      for (int nt = 0; nt < 4; ++nt){
        __syncthreads();               // protect Als/Bls readers (nt=0) / prev quarter readers
        int ci = wc*16 + (l & 15);     // 0..31 within quarter
        #pragma unroll
        for (int mt = 0; mt < 4; ++mt){
          int row = wr*64 + mt*16 + ((l >> 4) << 2);
          #pragma unroll
          for (int r = 0; r < 4; ++r)
            Tt[ci*129 + row + r] = -acc[mt][nt][r];
        }
        __syncthreads();
        int ci2 = t >> 3;              // 0..31
        int col = c0 + (ci2 >> 4)*64 + nt*16 + (ci2 & 15);
        if (col < HW){
          float* Drow = D + ((size_t)b*HW + col)*HW + r0;
          int rbase = (t & 7)*16;
          #pragma unroll
          for (int j = 0; j < 4; ++j){
            int rr = rbase + j*4;
            float4 v = make_float4(Tt[ci2*129 + rr],     Tt[ci2*129 + rr + 1],
                                   Tt[ci2*129 + rr + 2], Tt[ci2*129 + rr + 3]);
            *(float4*)(Drow + rr) = v;
          }
        }
      }
    }
  } else {
    #pragma unroll
    for (int mt = 0; mt < 4; ++mt){
      #pragma unroll
      for (int nt = 0; nt < 4; ++nt){
        int col = c0 + wc*64 + nt*16 + (l & 15);
        if (col >= HW) continue;
        int row0 = r0 + wr*64 + mt*16 + ((l >> 4) << 2);
        #pragma unroll
        for (int r = 0; r < 4; ++r){
          PQ[((size_t)b*768 + row0 + r)*HW + col] = acc[mt][nt][r];
        }
      }
    }
  }
}

// ---- 8. top-9 selection: one wave per row; idx stored [k][b*HW+n] ----
__global__ __launch_bounds__(256) void k_select(const float* __restrict__ D, int* __restrict__ idxo){
  int wid = threadIdx.x >> 6, lane = threadIdx.x & 63;
  int row = blockIdx.x * 4 + wid;            // [0, B*HW)
  const float* Dr = D + (size_t)row * HW;
  float dvv[13]; int mvv[13];
  #pragma unroll
  for (int i = 0; i < 13; ++i){
    int m = lane + 64*i;
    dvv[i] = (m < HW) ? Dr[m] : 3.4e38f;
    mvv[i] = m;
  }
  for (int k = 0; k < KK; ++k){
    float bd = dvv[0]; int bi = 0;
    #pragma unroll
    for (int i = 1; i < 13; ++i) if (dvv[i] < bd){ bd = dvv[i]; bi = i; }
    unsigned long long key = ((unsigned long long)f2ord(bd) << 32) | (unsigned)mvv[bi];
    for (int off = 32; off; off >>= 1){
      unsigned long long o = __shfl_xor(key, off);
      if (o < key) key = o;
    }
    int wm = (int)(unsigned)(key & 0xffffffffu);
    if (lane == 0) idxo[(size_t)k*(Bb*HW) + row] = wm;
    if (mvv[bi] == wm) dvv[bi] = 3.4e38f;
  }
}

// ---- 9. epilogue: Q rows staged in LDS; coalesced idx; amortized over 8 o ----
__global__ __launch_bounds__(256) void k_edge(const float* __restrict__ PQ, const int* __restrict__ idx,
                                              const float* __restrict__ be, float* __restrict__ out){
  int bid = blockIdx.x;
  int b = bid / (CO/OG), og = bid % (CO/OG);
  int o0 = og * OG;
  __shared__ float Qls[OG][HW + 4];
  const float* Qbase = PQ + ((size_t)b*768 + CO + o0)*HW;
  int t = threadIdx.x;
  #pragma unroll
  for (int oo = 0; oo < OG; ++oo){
    if (t < 196) *(float4*)&Qls[oo][t*4] = *(const float4*)(Qbase + (size_t)oo*HW + t*4);
  }
  __syncthreads();
  const float* Pbase = PQ + ((size_t)b*768 + o0)*HW;
  float bev[OG];
  #pragma unroll
  for (int oo = 0; oo < OG; ++oo) bev[oo] = be[o0 + oo];
  for (int n = t; n < HW; n += 256){
    int ip[KK];
    #pragma unroll
    for (int k = 0; k < KK; ++k) ip[k] = idx[(size_t)k*(Bb*HW) + b*HW + n];
    float qm[OG];
    #pragma unroll
    for (int oo = 0; oo < OG; ++oo) qm[oo] = -3.4e38f;
    #pragma unroll
    for (int k = 0; k < KK; ++k){
      int j = ip[k];
      #pragma unroll
      for (int oo = 0; oo < OG; ++oo) qm[oo] = fmaxf(qm[oo], Qls[oo][j]);
    }
    #pragma unroll
    for (int oo = 0; oo < OG; ++oo){
      out[((size_t)b*CO + o0 + oo)*HW + n] = fmaxf(Pbase[(size_t)oo*HW + n] + bev[oo] + qm[oo], 0.f);
    }
  }
}

extern "C" void kernel_launch(void* const* d_in, const int* in_sizes, int n_in,
                              void* d_out, int out_size, void* d_ws, size_t ws_size,
                              hipStream_t stream){
  const float* x   = (const float*)d_in[0];
  const float* we  = (const float*)d_in[1];
  const float* be  = (const float*)d_in[2];
  const float* w1  = (const float*)d_in[3];
  const float* b1  = (const float*)d_in[4];
  const float* w2  = (const float*)d_in[5];
  const float* b2  = (const float*)d_in[6];
  const float* wsp = (const float*)d_in[7];
  const float* bsp = (const float*)d_in[8];
  float* out = (float*)d_out;

  // workspace layout (~99 MiB of 256 MiB ws)
  float* ws    = (float*)d_ws;
  float* chm   = ws;                     // 3072
  float* chx   = chm + 3072;             // 3072
  float* chv   = chx + 3072;             // 3072
  float* vmaxA = chv + 3072;             // 3072
  float* invA  = vmaxA + 3072;           // 3072
  float* amean = invA + 3072;            // 12544
  float* amax  = amean + 12544;          // 12544
  float* satt  = amax + 12544;           // 12544
  float* nrm   = satt + 12544;           // 12544
  unsigned short* Wph = (unsigned short*)(nrm + 12544);    // 147456 ushorts
  unsigned short* Wpl = Wph + 147456;                      // 147456 ushorts
  unsigned short* Xnh = Wpl + 147456;    // 2408448 ushorts
  unsigned short* Xnl = Xnh + 2408448;   // 2408448 ushorts
  unsigned short* XAh = Xnl + 2408448;   // 2408448 ushorts
  unsigned short* XAl = XAh + 2408448;   // 2408448 ushorts
  int*   idx   = (int*)(XAl + 2408448);  // 112896 ints, layout [k][b*HW+n]
  float* D     = (float*)(idx + 112896); // 9834496 floats
  float* PQ    = D + 9834496;            // 9633792 floats (independent)

  k_chstats<<<768, 256, 0, stream>>>(x, chm, chx);
  k_mlp<<<16, 192, 0, stream>>>(chm, chx, w1, b1, w2, b2, chv);
  k_spin<<<64, 256, 0, stream>>>(x, chv, amean, amax, nrm);
  k_conv<<<64, 256, 0, stream>>>(amean, amax, wsp, bsp, satt);
  k_attstats<<<768, 256, 0, stream>>>(x, chv, satt, vmaxA, invA);
  k_cvt2wp<<<1200, 256, 0, stream>>>(x, nrm, chv, satt, vmaxA, invA, we,
                                     Xnh, Xnl, XAh, XAl, Wph, Wpl);
  k_gramgemm<<<1120, 256, 0, stream>>>(Xnh, Xnl, Wph, Wpl, XAh, XAl, D, PQ);
  k_select<<<3136, 256, 0, stream>>>(D, idx);
  k_edge<<<Bb*(CO/OG), 256, 0, stream>>>(PQ, idx, be, out);
}